// Round 7
// baseline (235.926 us; speedup 1.0000x reference)
//
#include <hip/hip_runtime.h>
#include <stdint.h>

#define N_NODES 4096
#define N_EDGES 131072

typedef __attribute__((ext_vector_type(8))) short short8;
typedef __attribute__((ext_vector_type(4))) float floatx4;

__device__ __forceinline__ float bf2f(unsigned short u) {
  union { unsigned u; float f; } v; v.u = ((unsigned)u) << 16; return v.f;
}
__device__ __forceinline__ unsigned short f2bf(float f) {
  union { float f; unsigned u; } v; v.f = f;
  unsigned r = 0x7FFFu + ((v.u >> 16) & 1u);
  return (unsigned short)((v.u + r) >> 16);
}
__device__ __forceinline__ float wredsum(float x) {
#pragma unroll
  for (int d = 32; d >= 1; d >>= 1) x += __shfl_xor(x, d);
  return x;
}
__device__ __forceinline__ float wredmax(float x) {
#pragma unroll
  for (int d = 32; d >= 1; d >>= 1) x = fmaxf(x, __shfl_xor(x, d));
  return x;
}
__device__ __forceinline__ void gload16(const void* g, void* l) {
  __builtin_amdgcn_global_load_lds(
      (const __attribute__((address_space(1))) unsigned*)g,
      (__attribute__((address_space(3))) unsigned*)l, 16, 0, 0);
}

// ============ 128x128-tile GEMM, BK=32, XOR-swizzled LDS (m97-style) ======
// Fused epilogue: optional per-head src/dst projections (Wh . a) via 16-lane
// shuffle reduce + atomicAdd into sdv (must be pre-zeroed).
__global__ __launch_bounds__(256) void gemm128(
    const unsigned short* __restrict__ A, const unsigned short* __restrict__ Bt,
    int M, int N, int K, unsigned short* __restrict__ Cb,
    const float* __restrict__ avec, float* __restrict__ sdv, int FO) {
  __shared__ __align__(16) unsigned short As[128 * 32];
  __shared__ __align__(16) unsigned short Bs[128 * 32];
  const int t = threadIdx.x, lane = t & 63, w = t >> 6;
  const int wr = w >> 1, wc = w & 1;
  const int n0 = blockIdx.x * 128, m0 = blockIdx.y * 128;
  floatx4 acc[4][4] = {};
  const int arow = t >> 2;                          // 0..63
  const int schunk = (t & 3) ^ ((arow >> 1) & 3);   // pre-swizzled src chunk

  for (int kt = 0; kt < K; kt += 32) {
    __syncthreads();
    gload16(A + (size_t)(m0 + arow) * K + kt + schunk * 8, &As[t * 8]);
    gload16(A + (size_t)(m0 + 64 + arow) * K + kt + schunk * 8, &As[(256 + t) * 8]);
    gload16(Bt + (size_t)(n0 + arow) * K + kt + schunk * 8, &Bs[t * 8]);
    gload16(Bt + (size_t)(n0 + 64 + arow) * K + kt + schunk * 8, &Bs[(256 + t) * 8]);
    __syncthreads();
    short8 af[4], bfr[4];
    const int koff = lane >> 4;
#pragma unroll
    for (int m = 0; m < 4; ++m) {
      const int r = wr * 64 + (lane & 15) + m * 16;
      af[m] = *(const short8*)&As[r * 32 + ((koff ^ ((r >> 1) & 3)) << 3)];
    }
#pragma unroll
    for (int n = 0; n < 4; ++n) {
      const int r = wc * 64 + (lane & 15) + n * 16;
      bfr[n] = *(const short8*)&Bs[r * 32 + ((koff ^ ((r >> 1) & 3)) << 3)];
    }
#pragma unroll
    for (int m = 0; m < 4; ++m)
#pragma unroll
      for (int n = 0; n < 4; ++n)
        acc[m][n] = __builtin_amdgcn_mfma_f32_16x16x32_bf16(af[m], bfr[n], acc[m][n], 0, 0, 0);
  }

  const int rb = m0 + wr * 64 + (lane >> 4) * 4;
  const int cb = n0 + wc * 64 + (lane & 15);
#pragma unroll
  for (int m = 0; m < 4; ++m)
#pragma unroll
    for (int n = 0; n < 4; ++n) {
      const int col = cb + n * 16;
#pragma unroll
      for (int r = 0; r < 4; ++r) {
        const int row = rb + m * 16 + r;
        Cb[(size_t)row * N + col] = f2bf(acc[m][n][r]);
      }
    }

  if (avec) {  // fused src/dst projections
    const int h = n0 / FO;       // block lies within one head (128 | FO)
    const int cw0 = cb - h * FO; // col-in-head for n=0
    float as_[4], ad_[4];
#pragma unroll
    for (int n = 0; n < 4; ++n) {
      as_[n] = avec[h * 2 * FO + cw0 + n * 16];
      ad_[n] = avec[h * 2 * FO + FO + cw0 + n * 16];
    }
#pragma unroll
    for (int m = 0; m < 4; ++m)
#pragma unroll
      for (int r = 0; r < 4; ++r) {
        float sp = 0.f, dp = 0.f;
#pragma unroll
        for (int n = 0; n < 4; ++n) {
          sp += acc[m][n][r] * as_[n];
          dp += acc[m][n][r] * ad_[n];
        }
#pragma unroll
        for (int d = 1; d < 16; d <<= 1) {
          sp += __shfl_xor(sp, d);
          dp += __shfl_xor(dp, d);
        }
        if ((lane & 15) == 0) {
          const int row = rb + m * 16 + r;
          atomicAdd(&sdv[row * 8 + h], sp);
          atomicAdd(&sdv[row * 8 + 4 + h], dp);
        }
      }
  }
}

// ================= 64x64-tile GEMM, BK=64, XOR-swizzled LDS ===============
__device__ __forceinline__ void stage64(const unsigned short* __restrict__ G,
                                        unsigned short* lds, int row0, int K,
                                        int kt, int t) {
  const int l0 = t, l1 = t + 256;
  const int r0 = l0 >> 3, c0 = l0 & 7;
  const int r1 = l1 >> 3, c1 = l1 & 7;
  gload16(G + (size_t)(row0 + r0) * K + kt + ((c0 ^ (r0 & 7)) << 3), &lds[l0 * 8]);
  gload16(G + (size_t)(row0 + r1) * K + kt + ((c1 ^ (r1 & 7)) << 3), &lds[l1 * 8]);
}
__device__ __forceinline__ short8 frag64(const unsigned short* lds, int r, int c) {
  return *(const short8*)&lds[r * 64 + ((c ^ (r & 7)) << 3)];
}

// EP: 4 = relu(acc+bias[col]) -> bf16 (decoder layer 1)
template <int EP>
__global__ __launch_bounds__(256) void gemm64(
    const unsigned short* __restrict__ A, const unsigned short* __restrict__ Bt,
    int M, int N, int K, unsigned short* __restrict__ Cb,
    const float* __restrict__ bias) {
  __shared__ __align__(16) unsigned short As[64 * 64];
  __shared__ __align__(16) unsigned short Bs[64 * 64];
  const int t = threadIdx.x, lane = t & 63, w = t >> 6;
  const int wr = w >> 1, wc = w & 1;
  const int n0 = blockIdx.x * 64, m0 = blockIdx.y * 64;
  floatx4 acc[2][2] = {};

  for (int kt = 0; kt < K; kt += 64) {
    __syncthreads();
    stage64(A, As, m0, K, kt, t);
    stage64(Bt, Bs, n0, K, kt, t);
    __syncthreads();
    short8 af[2][2], bfv[2][2];
#pragma unroll
    for (int m = 0; m < 2; ++m) {
      const int ra = wr * 32 + (lane & 15) + m * 16;
#pragma unroll
      for (int kk = 0; kk < 2; ++kk)
        af[m][kk] = frag64(As, ra, (lane >> 4) + kk * 4);
    }
#pragma unroll
    for (int n = 0; n < 2; ++n) {
      const int rb = wc * 32 + (lane & 15) + n * 16;
#pragma unroll
      for (int kk = 0; kk < 2; ++kk)
        bfv[n][kk] = frag64(Bs, rb, (lane >> 4) + kk * 4);
    }
#pragma unroll
    for (int kk = 0; kk < 2; ++kk)
#pragma unroll
      for (int m = 0; m < 2; ++m)
#pragma unroll
        for (int n = 0; n < 2; ++n)
          acc[m][n] = __builtin_amdgcn_mfma_f32_16x16x32_bf16(af[m][kk], bfv[n][kk], acc[m][n], 0, 0, 0);
  }

  const int rb = m0 + wr * 32 + (lane >> 4) * 4;
  const int cb = n0 + wc * 32 + (lane & 15);
#pragma unroll
  for (int m = 0; m < 2; ++m)
#pragma unroll
    for (int n = 0; n < 2; ++n) {
      const int col = cb + n * 16;
#pragma unroll
      for (int r = 0; r < 4; ++r) {
        const int row = rb + m * 16 + r;
        float v = acc[m][n][r];
        if (EP == 4) { v += bias[col]; v = v > 0.f ? v : 0.f; }
        Cb[(size_t)row * N + col] = f2bf(v);
      }
    }
}

// C = relu(elu(A1@B1t) + A2@B2t).  EP0: bf16 store (merged).
// EP1: f32 store split — rows<4096 -> Cfo, rows>=4096 -> Cfa.
template <int EP>
__global__ __launch_bounds__(256) void gemm64dual(
    const unsigned short* __restrict__ A1, const unsigned short* __restrict__ B1t, int K1,
    const unsigned short* __restrict__ A2, const unsigned short* __restrict__ B2t, int K2,
    int N, unsigned short* __restrict__ Cb,
    float* __restrict__ Cfo, float* __restrict__ Cfa) {
  __shared__ __align__(16) unsigned short As[64 * 64];
  __shared__ __align__(16) unsigned short Bs[64 * 64];
  const int t = threadIdx.x, lane = t & 63, w = t >> 6;
  const int wr = w >> 1, wc = w & 1;
  const int n0 = blockIdx.x * 64, m0 = blockIdx.y * 64;
  floatx4 acc[2][2] = {};

#pragma unroll 1
  for (int pass = 0; pass < 2; ++pass) {
    const unsigned short* A = pass ? A2 : A1;
    const unsigned short* Bt = pass ? B2t : B1t;
    const int K = pass ? K2 : K1;
    for (int kt = 0; kt < K; kt += 64) {
      __syncthreads();
      stage64(A, As, m0, K, kt, t);
      stage64(Bt, Bs, n0, K, kt, t);
      __syncthreads();
      short8 af[2][2], bfv[2][2];
#pragma unroll
      for (int m = 0; m < 2; ++m) {
        const int ra = wr * 32 + (lane & 15) + m * 16;
#pragma unroll
        for (int kk = 0; kk < 2; ++kk)
          af[m][kk] = frag64(As, ra, (lane >> 4) + kk * 4);
      }
#pragma unroll
      for (int n = 0; n < 2; ++n) {
        const int rb = wc * 32 + (lane & 15) + n * 16;
#pragma unroll
        for (int kk = 0; kk < 2; ++kk)
          bfv[n][kk] = frag64(Bs, rb, (lane >> 4) + kk * 4);
      }
#pragma unroll
      for (int kk = 0; kk < 2; ++kk)
#pragma unroll
        for (int m = 0; m < 2; ++m)
#pragma unroll
          for (int n = 0; n < 2; ++n)
            acc[m][n] = __builtin_amdgcn_mfma_f32_16x16x32_bf16(af[m][kk], bfv[n][kk], acc[m][n], 0, 0, 0);
    }
    if (pass == 0) {
#pragma unroll
      for (int m = 0; m < 2; ++m)
#pragma unroll
        for (int n = 0; n < 2; ++n)
#pragma unroll
          for (int r = 0; r < 4; ++r) {
            float v = acc[m][n][r];
            acc[m][n][r] = v > 0.f ? v : expm1f(v);
          }
    }
  }

  const int rb = m0 + wr * 32 + (lane >> 4) * 4;
  const int cb = n0 + wc * 32 + (lane & 15);
#pragma unroll
  for (int m = 0; m < 2; ++m)
#pragma unroll
    for (int n = 0; n < 2; ++n) {
      const int col = cb + n * 16;
#pragma unroll
      for (int r = 0; r < 4; ++r) {
        const int row = rb + m * 16 + r;
        float v = acc[m][n][r];
        v = v > 0.f ? v : 0.f;
        if (EP == 0) {
          Cb[(size_t)row * N + col] = f2bf(v);
        } else {
          float* bb = (row < 4096) ? Cfo : Cfa;
          bb[(size_t)(row & 4095) * N + col] = v;
        }
      }
    }
}

// ---------------- mask scatter + sd zero ---------------------------------
__global__ __launch_bounds__(256) void scatter_kernel(
    const int* __restrict__ ei, unsigned long long* __restrict__ mb,
    float* __restrict__ sd1, float* __restrict__ sd2) {
  int b = blockIdx.x;
  if (b < 512) {
    int e = b * 256 + threadIdx.x;
    int r = ei[e], c = ei[N_EDGES + e];
    atomicOr(&mb[(size_t)r * 64 + (c >> 6)], 1ull << (c & 63));
  } else {  // zero sd1 (65536 floats) then sd2
    int z = (b - 512) * 256 + threadIdx.x;
    if (z < 65536) sd1[z] = 0.f;
    else sd2[z - 65536] = 0.f;
  }
}

// ---------------- weight pack: tiled f32->bf16 transposes + x casts -------
__global__ __launch_bounds__(256) void pack2_kernel(
    const float* W1, const float* lin1, const float* res1, const float* W2,
    const float* lin2, const float* res2, const float* dec1,
    const float* xo, const float* xa,
    unsigned short* dW1, unsigned short* dlin1, unsigned short* dres1,
    unsigned short* dW2, unsigned short* dlin2, unsigned short* dres2,
    unsigned short* ddec1, unsigned short* x16) {
  const int b = blockIdx.x, t = threadIdx.x;
  if (b >= 1248) {  // x_o / x_a f32 -> bf16 into merged [8192][512]
    int ib = b - 1248;
    const float* src = (ib < 512) ? xo : xa;
    unsigned short* dst = x16 + ((ib < 512) ? 0 : (size_t)4096 * 512);
    size_t base = (size_t)(ib & 511) * 4096;
#pragma unroll
    for (int q = 0; q < 4; ++q) {
      size_t o = base + q * 1024 + t * 4;
      float4 v = *(const float4*)&src[o];
      ushort4 u = {f2bf(v.x), f2bf(v.y), f2bf(v.z), f2bf(v.w)};
      *(ushort4*)&dst[o] = u;
    }
    return;
  }
  const float* src; unsigned short* dst; int K, F, nFt, tb;
  if (b < 512)       { int h = b >> 7;        src = W1 + h * 131072; dst = dW1 + h * 131072; K = 512;  F = 256; nFt = 8;  tb = b & 127; }
  else if (b < 768)  {                        src = lin1;            dst = dlin1;            K = 1024; F = 256; nFt = 8;  tb = b - 512; }
  else if (b < 896)  {                        src = res1;            dst = dres1;            K = 512;  F = 256; nFt = 8;  tb = b - 768; }
  else if (b < 1024) { int h = (b - 896) >> 5; src = W2 + h * 32768; dst = dW2 + h * 32768;  K = 256;  F = 128; nFt = 4;  tb = (b - 896) & 31; }
  else if (b < 1088) {                        src = lin2;            dst = dlin2;            K = 512;  F = 128; nFt = 4;  tb = b - 1024; }
  else if (b < 1120) {                        src = res2;            dst = dres2;            K = 256;  F = 128; nFt = 4;  tb = b - 1088; }
  else               {                        src = dec1;            dst = ddec1;            K = 256;  F = 512; nFt = 16; tb = b - 1120; }
  const int k0 = (tb / nFt) * 32, f0 = (tb % nFt) * 32;
  __shared__ float tile[32][33];
  {
    int r = t >> 3, c4 = (t & 7) * 4;
    float4 v = *(const float4*)&src[(size_t)(k0 + r) * F + f0 + c4];
    tile[r][c4] = v.x; tile[r][c4 + 1] = v.y; tile[r][c4 + 2] = v.z; tile[r][c4 + 3] = v.w;
  }
  __syncthreads();
  {
    int f = t >> 3, k4 = (t & 7) * 4;
    ushort4 u;
    u.x = f2bf(tile[k4 + 0][f]); u.y = f2bf(tile[k4 + 1][f]);
    u.z = f2bf(tile[k4 + 2][f]); u.w = f2bf(tile[k4 + 3][f]);
    *(ushort4*)&dst[(size_t)(f0 + f) * K + k0 + k4] = u;
  }
}

// ------- sparse masked softmax attention + elu (2-deep pipelined gather) --
// R5 structure (wave == head). Pass 3 software-pipelines 8-neighbor groups
// two deep: loads for group g+2/g+3 issue while groups g/g+1 are FMA'd.
// nbr/wgs are zero-padded 32 entries so prefetch needs no bounds checks.
template <int FO>
__global__ __launch_bounds__(256) void attn_kernel(
    const unsigned long long* __restrict__ mb, const float* __restrict__ sd,
    const unsigned short* __restrict__ Wh, unsigned short* __restrict__ outp) {
  constexpr int E = FO / 64;
  constexpr int W = 4 * FO;
  constexpr int WGCAP = 512;  // multiple of 8
  __shared__ unsigned short nbr[4136];   // 4096 + 40 pad
  __shared__ float wgs[4][WGCAP + 32];
  __shared__ int s_cnt;
  const int i = blockIdx.x;            // 0..8191 (two encodes)
  const int mrow = i & 4095;           // mask row
  const int base = i & ~4095;          // 0 or 4096: row offset into Wh/sd
  const int t = threadIdx.x;
  const int lane = t & 63, h = t >> 6;

  if (t < 64) {  // wave 0 builds the deduped neighbor list from the bitmask
    unsigned long long wb = mb[(size_t)mrow * 64 + t];
    int pc = __popcll(wb);
    int inc = pc;
#pragma unroll
    for (int d = 1; d < 64; d <<= 1) {
      int v = __shfl_up(inc, d);
      if (t >= d) inc += v;
    }
    if (t == 63) s_cnt = inc;
    int off = inc - pc;
    while (wb) {
      int b = __builtin_ctzll(wb);
      nbr[off++] = (unsigned short)(t * 64 + b);
      wb &= wb - 1;
    }
  }
  __syncthreads();
  const int cnt = s_cnt;
  if (t < 40) nbr[(cnt + t < 4135) ? cnt + t : 4135] = 0;  // pad
  const float src_i = sd[(size_t)i * 8 + h];
  float acc[E] = {};
  float inv = 1.f;
  if (cnt > 0) {
    // pass 1: row max (lane-parallel)
    float m = -1e30f;
    for (int nn = lane; nn < cnt; nn += 64) {
      int j = base + nbr[nn];
      float x = src_i + sd[(size_t)j * 8 + 4 + h];
      m = fmaxf(m, x > 0.f ? x : 0.2f * x);
    }
    m = wredmax(m);
    // pass 2: unnormalized weights -> LDS, sum (lane-parallel)
    float ssum = 0.f;
    for (int nn = lane; nn < cnt; nn += 64) {
      int j = base + nbr[nn];
      float x = src_i + sd[(size_t)j * 8 + 4 + h];
      float e = x > 0.f ? x : 0.2f * x;
      float g = __expf(e - m);
      if (nn < WGCAP) wgs[h][nn] = g;
      ssum += g;
    }
    ssum = wredsum(ssum);
    inv = 1.f / ssum;
    const int limc = cnt < WGCAP ? cnt : WGCAP;
    if (lane < 32) wgs[h][limc + lane] = 0.f;  // zero pad
    __builtin_amdgcn_s_barrier();  // nbr/wgs pads visible before pass 3
    // pass 3: 2-deep pipelined 8-groups
    const int ngroups = (limc + 7) >> 3;       // >= 1
    const int ngr = (ngroups + 1) & ~1;        // even
    if constexpr (E == 4) {
      uint2 rA[8], rB[8];
#define LD8x2(R, g)                                                         \
  {                                                                          \
    const int nn_ = (g) * 8;                                                 \
    ushort4 ja_ = *(const ushort4*)&nbr[nn_];                                \
    ushort4 jb_ = *(const ushort4*)&nbr[nn_ + 4];                            \
    R[0] = *(const uint2*)(Wh + (size_t)(base + ja_.x) * W + h * FO + lane * 4); \
    R[1] = *(const uint2*)(Wh + (size_t)(base + ja_.y) * W + h * FO + lane * 4); \
    R[2] = *(const uint2*)(Wh + (size_t)(base + ja_.z) * W + h * FO + lane * 4); \
    R[3] = *(const uint2*)(Wh + (size_t)(base + ja_.w) * W + h * FO + lane * 4); \
    R[4] = *(const uint2*)(Wh + (size_t)(base + jb_.x) * W + h * FO + lane * 4); \
    R[5] = *(const uint2*)(Wh + (size_t)(base + jb_.y) * W + h * FO + lane * 4); \
    R[6] = *(const uint2*)(Wh + (size_t)(base + jb_.z) * W + h * FO + lane * 4); \
    R[7] = *(const uint2*)(Wh + (size_t)(base + jb_.w) * W + h * FO + lane * 4); \
  }
#define FMA8x2(R, g)                                                         \
  {                                                                          \
    const int nn_ = (g) * 8;                                                 \
    float4 wa_ = *(const float4*)&wgs[h][nn_];                               \
    float4 wb_ = *(const float4*)&wgs[h][nn_ + 4];                           \
    const float ws_[8] = {wa_.x, wa_.y, wa_.z, wa_.w,                        \
                          wb_.x, wb_.y, wb_.z, wb_.w};                       \
    _Pragma("unroll") for (int q = 0; q < 8; ++q) {                          \
      acc[0] += ws_[q] * bf2f((unsigned short)(R[q].x & 0xffff));            \
      acc[1] += ws_[q] * bf2f((unsigned short)(R[q].x >> 16));               \
      acc[2] += ws_[q] * bf2f((unsigned short)(R[q].y & 0xffff));            \
      acc[3] += ws_[q] * bf2f((unsigned short)(R[q].y >> 16));               \
    }                                                                        \
  }
      LD8x2(rA, 0);
      LD8x2(rB, 1);
      for (int g = 0; g < ngr; g += 2) {
        FMA8x2(rA, g);
        LD8x2(rA, g + 2);
        FMA8x2(rB, g + 1);
        LD8x2(rB, g + 3);
      }
#undef LD8x2
#undef FMA8x2
    } else {
      unsigned rA[8], rB[8];
#define LD8x1(R, g)                                                          \
  {                                                                          \
    const int nn_ = (g) * 8;                                                 \
    ushort4 ja_ = *(const ushort4*)&nbr[nn_];                                \
    ushort4 jb_ = *(const ushort4*)&nbr[nn_ + 4];                            \
    R[0] = *(const unsigned*)(Wh + (size_t)(base + ja_.x) * W + h * FO + lane * 2); \
    R[1] = *(const unsigned*)(Wh + (size_t)(base + ja_.y) * W + h * FO + lane * 2); \
    R[2] = *(const unsigned*)(Wh + (size_t)(base + ja_.z) * W + h * FO + lane * 2); \
    R[3] = *(const unsigned*)(Wh + (size_t)(base + ja_.w) * W + h * FO + lane * 2); \
    R[4] = *(const unsigned*)(Wh + (size_t)(base + jb_.x) * W + h * FO + lane * 2); \
    R[5] = *(const unsigned*)(Wh + (size_t)(base + jb_.y) * W + h * FO + lane * 2); \
    R[6] = *(const unsigned*)(Wh + (size_t)(base + jb_.z) * W + h * FO + lane * 2); \
    R[7] = *(const unsigned*)(Wh + (size_t)(base + jb_.w) * W + h * FO + lane * 2); \
  }
#define FMA8x1(R, g)                                                         \
  {                                                                          \
    const int nn_ = (g) * 8;                                                 \
    float4 wa_ = *(const float4*)&wgs[h][nn_];                               \
    float4 wb_ = *(const float4*)&wgs[h][nn_ + 4];                           \
    const float ws_[8] = {wa_.x, wa_.y, wa_.z, wa_.w,                        \
                          wb_.x, wb_.y, wb_.z, wb_.w};                       \
    _Pragma("unroll") for (int q = 0; q < 8; ++q) {                          \
      acc[0] += ws_[q] * bf2f((unsigned short)(R[q] & 0xffff));              \
      acc[1] += ws_[q] * bf2f((unsigned short)(R[q] >> 16));                 \
    }                                                                        \
  }
      LD8x1(rA, 0);
      LD8x1(rB, 1);
      for (int g = 0; g < ngr; g += 2) {
        FMA8x1(rA, g);
        LD8x1(rA, g + 2);
        FMA8x1(rB, g + 1);
        LD8x1(rB, g + 3);
      }
#undef LD8x1
#undef FMA8x1
    }
    // tail beyond WGCAP: recompute weights inline (unreachable for this input)
    for (int nn = WGCAP; nn < cnt; ++nn) {
      int j = base + nbr[nn];
      float x = src_i + sd[(size_t)j * 8 + 4 + h];
      float e = x > 0.f ? x : 0.2f * x;
      float g = __expf(e - m);
      const unsigned short* p = Wh + (size_t)j * W + h * FO + lane * E;
#pragma unroll
      for (int q = 0; q < E; ++q) acc[q] += g * bf2f(p[q]);
    }
  } else {  // all-masked row: softmax over NEG row is uniform 1/N
    const float wg = 1.f / 4096.f;
    for (int j = 0; j < N_NODES; ++j) {
      const unsigned short* p = Wh + (size_t)(base + j) * W + h * FO + lane * E;
#pragma unroll
      for (int q = 0; q < E; ++q) acc[q] += wg * bf2f(p[q]);
    }
  }
  unsigned short* op = outp + (size_t)i * W + h * FO + lane * E;
#pragma unroll
  for (int q = 0; q < E; ++q) {
    float v = acc[q] * inv;
    op[q] = f2bf(v > 0.f ? v : expm1f(v));
  }
}

// ---------------- column sums of x2 (for mean) ---------------------------
__global__ __launch_bounds__(128) void colsum_kernel(
    const float* __restrict__ x2o, const float* __restrict__ x2a,
    float* __restrict__ small) {
  int b = blockIdx.x, f = threadIdx.x;
  const float* x = (b < 64) ? x2o : x2a;
  float* s = (b < 64) ? small : (small + 128);
  int r0 = (b & 63) * 64;
  float acc = 0.f;
  for (int r = 0; r < 64; ++r) acc += x[(size_t)(r0 + r) * 128 + f];
  atomicAdd(&s[f], acc);
}

// ---------------- tiny head math (single block) --------------------------
__global__ __launch_bounds__(128) void finalize_kernel(
    float* __restrict__ small, const float* __restrict__ mlp1_w,
    const float* __restrict__ mlp1_b, const float* __restrict__ disc_w,
    const float* __restrict__ adv_w, const float* __restrict__ adv_b) {
  __shared__ float so[128], sa[128], ho[128], ha[128];
  int f = threadIdx.x;
  so[f] = 1.f / (1.f + __expf(-small[f] * (1.f / 4096.f)));
  sa[f] = 1.f / (1.f + __expf(-small[128 + f] * (1.f / 4096.f)));
  __syncthreads();
  float aco = mlp1_b[f], aca = mlp1_b[f];
  for (int c = 0; c < 128; ++c) {
    aco += so[c] * mlp1_w[c * 128 + f];
    aca += sa[c] * mlp1_w[c * 128 + f];
  }
  ho[f] = aco;
  ha[f] = aca;
  __syncthreads();
  float vo = 0.f, va = 0.f, ar = 0.f;
  for (int c = 0; c < 128; ++c) {
    vo += disc_w[f * 128 + c] * ho[c];
    va += disc_w[f * 128 + c] * ha[c];
    ar += adv_w[f * 128 + c];
  }
  small[256 + f] = vo;
  small[384 + f] = va;
  small[512 + f] = ar;
  if (f == 0) {
    float b = 0.f;
    for (int c = 0; c < 128; ++c) b += adv_b[c];
    small[640] = b;
  }
}

// ---------------- per-node disc / adv outputs ----------------------------
__global__ __launch_bounds__(256) void pernode_kernel(
    const float* __restrict__ x2o, const float* __restrict__ x2a,
    const float* __restrict__ small, const float* __restrict__ disc_b,
    float* __restrict__ out) {
  const float* v_os = small + 256;
  const float* v_a = small + 384;
  const float* adv_rs = small + 512;
  int lane = threadIdx.x & 63, wv = threadIdx.x >> 6;
  int i = blockIdx.x * 4 + wv;
  float2 xo = *(const float2*)&x2o[(size_t)i * 128 + lane * 2];
  float2 xa = *(const float2*)&x2a[(size_t)i * 128 + lane * 2];
  float2 vo = *(const float2*)&v_os[lane * 2];
  float2 va = *(const float2*)&v_a[lane * 2];
  float2 ar = *(const float2*)&adv_rs[lane * 2];
  float poo = wredsum(xo.x * vo.x + xo.y * vo.y);
  float pao = wredsum(xa.x * vo.x + xa.y * vo.y);
  float paa = wredsum(xa.x * va.x + xa.y * va.y);
  float poa = wredsum(xo.x * va.x + xo.y * va.y);
  float pov = wredsum(xo.x * ar.x + xo.y * ar.y);
  float pav = wredsum(xa.x * ar.x + xa.y * ar.y);
  if (lane == 0) {
    float db = disc_b[0], bv = small[640];
    out[4096 + 2 * i] = poo + db;
    out[4096 + 2 * i + 1] = pao + db;
    out[12288 + 2 * i] = paa + db;
    out[12288 + 2 * i + 1] = poa + db;
    out[544768 + i] = pov + bv;
    out[548864 + i] = pav + bv;
  }
}

// ---------------- decoder gather / final dot -----------------------------
__global__ __launch_bounds__(256) void gather_kernel(
    const float* __restrict__ x2o, const int* __restrict__ idx,
    unsigned short* __restrict__ z) {
  int i = blockIdx.x, c = threadIdx.x;
  int s = (c < 128) ? idx[i] : idx[4096 + i];
  z[(size_t)i * 256 + c] = f2bf(x2o[(size_t)s * 128 + (c & 127)]);
}

__global__ __launch_bounds__(256) void dec2_kernel(
    const unsigned short* __restrict__ hdec, const float* __restrict__ w2,
    const float* __restrict__ b2, float* __restrict__ out) {
  int lane = threadIdx.x & 63, wv = threadIdx.x >> 6;
  int i = blockIdx.x * 4 + wv;
  float s = 0.f;
#pragma unroll
  for (int q = 0; q < 8; ++q) {
    int f = lane + q * 64;
    s += bf2f(hdec[(size_t)i * 512 + f]) * w2[f];
  }
  s = wredsum(s);
  if (lane == 0) {
    float v = s + b2[0];
    out[552960 + i] = v;           // log1
    out[i] = 1.f / (1.f + __expf(-v));  // log
  }
}

// ---------------- host orchestration -------------------------------------
extern "C" void kernel_launch(void* const* d_in, const int* in_sizes, int n_in,
                              void* d_out, int out_size, void* d_ws, size_t ws_size,
                              hipStream_t stream) {
  const float* x_o = (const float*)d_in[0];
  const float* x_a = (const float*)d_in[1];
  const int* ei = (const int*)d_in[2];
  const int* idx = (const int*)d_in[3];
  const float* W1 = (const float*)d_in[4];
  const float* a1 = (const float*)d_in[5];
  const float* lin1 = (const float*)d_in[6];
  const float* res1 = (const float*)d_in[7];
  const float* W2 = (const float*)d_in[8];
  const float* a2 = (const float*)d_in[9];
  const float* lin2 = (const float*)d_in[10];
  const float* res2 = (const float*)d_in[11];
  const float* mlp1_w = (const float*)d_in[12];
  const float* mlp1_b = (const float*)d_in[13];
  const float* disc_w = (const float*)d_in[14];
  const float* disc_b = (const float*)d_in[15];
  const float* dec1_w = (const float*)d_in[16];
  const float* dec1_b = (const float*)d_in[17];
  const float* dec2_w = (const float*)d_in[18];
  const float* dec2_b = (const float*)d_in[19];
  const float* adv_w = (const float*)d_in[20];
  const float* adv_b = (const float*)d_in[21];
  float* out = (float*)d_out;

  char* w = (char*)d_ws;
  size_t off = 0;
  auto alloc = [&](size_t b) {
    char* p = w + off;
    off += (b + 255) & ~(size_t)255;
    return p;
  };
  unsigned long long* mb = (unsigned long long*)alloc((size_t)4096 * 64 * 8);
  unsigned short* x16 = (unsigned short*)alloc((size_t)8192 * 512 * 2);
  unsigned short* Wh1 = (unsigned short*)alloc((size_t)8192 * 1024 * 2);
  unsigned short* ho1 = (unsigned short*)alloc((size_t)8192 * 1024 * 2);
  unsigned short* h1 = (unsigned short*)alloc((size_t)8192 * 256 * 2);
  unsigned short* Wh2 = (unsigned short*)alloc((size_t)8192 * 512 * 2);
  unsigned short* ho2 = (unsigned short*)alloc((size_t)8192 * 512 * 2);
  float* x2a = (float*)alloc((size_t)4096 * 128 * 4);
  float* sd1 = (float*)alloc((size_t)8192 * 8 * 4);
  float* sd2 = (float*)alloc((size_t)8192 * 8 * 4);
  float* small = (float*)alloc(1024 * 4);
  unsigned short* tW1 = (unsigned short*)alloc((size_t)524288 * 2);
  unsigned short* tlin1 = (unsigned short*)alloc((size_t)262144 * 2);
  unsigned short* tres1 = (unsigned short*)alloc((size_t)131072 * 2);
  unsigned short* tW2 = (unsigned short*)alloc((size_t)131072 * 2);
  unsigned short* tlin2 = (unsigned short*)alloc((size_t)65536 * 2);
  unsigned short* tres2 = (unsigned short*)alloc((size_t)32768 * 2);
  unsigned short* tdec1 = (unsigned short*)alloc((size_t)131072 * 2);
  unsigned short* z16 = (unsigned short*)alloc((size_t)4096 * 256 * 2);
  unsigned short* hdec = (unsigned short*)alloc((size_t)4096 * 512 * 2);

  hipMemsetAsync(mb, 0, (size_t)4096 * 64 * 8, stream);
  hipMemsetAsync(small, 0, 1024, stream);  // colsum accumulators
  scatter_kernel<<<1024, 256, 0, stream>>>(ei, mb, sd1, sd2);
  pack2_kernel<<<2272, 256, 0, stream>>>(W1, lin1, res1, W2, lin2, res2, dec1_w,
                                         x_o, x_a, tW1, tlin1, tres1, tW2,
                                         tlin2, tres2, tdec1, x16);

  float* x2o_out = out + 20480;  // x2_o lives directly in d_out

  // ---- merged encode (rows 0..4095 = x_o, 4096..8191 = x_a) ----
  gemm128<<<dim3(8, 64), 256, 0, stream>>>(x16, tW1, 8192, 1024, 512, Wh1, a1, sd1, 256);
  attn_kernel<256><<<8192, 256, 0, stream>>>(mb, sd1, Wh1, ho1);
  gemm64dual<0><<<dim3(4, 128), 256, 0, stream>>>(ho1, tlin1, 1024, x16, tres1, 512, 256, h1, nullptr, nullptr);
  gemm128<<<dim3(4, 64), 256, 0, stream>>>(h1, tW2, 8192, 512, 256, Wh2, a2, sd2, 128);
  attn_kernel<128><<<8192, 256, 0, stream>>>(mb, sd2, Wh2, ho2);
  gemm64dual<1><<<dim3(2, 128), 256, 0, stream>>>(ho2, tlin2, 512, h1, tres2, 256, 128, nullptr, x2o_out, x2a);

  colsum_kernel<<<128, 128, 0, stream>>>(x2o_out, x2a, small);
  finalize_kernel<<<1, 128, 0, stream>>>(small, mlp1_w, mlp1_b, disc_w, adv_w, adv_b);
  pernode_kernel<<<1024, 256, 0, stream>>>(x2o_out, x2a, small, disc_b, out);
  gather_kernel<<<4096, 256, 0, stream>>>(x2o_out, idx, z16);
  gemm64<4><<<dim3(8, 64), 256, 0, stream>>>(z16, tdec1, 4096, 512, 256, hdec, dec1_b);
  dec2_kernel<<<1024, 256, 0, stream>>>(hdec, dec2_w, dec2_b, out);
}

// Round 8
// 229.629 us; speedup vs baseline: 1.0274x; 1.0274x over previous
//
#include <hip/hip_runtime.h>
#include <stdint.h>

#define N_NODES 4096
#define N_EDGES 131072

typedef __attribute__((ext_vector_type(8))) short short8;
typedef __attribute__((ext_vector_type(4))) float floatx4;

__device__ __forceinline__ float bf2f(unsigned short u) {
  union { unsigned u; float f; } v; v.u = ((unsigned)u) << 16; return v.f;
}
__device__ __forceinline__ unsigned short f2bf(float f) {
  union { float f; unsigned u; } v; v.f = f;
  unsigned r = 0x7FFFu + ((v.u >> 16) & 1u);
  return (unsigned short)((v.u + r) >> 16);
}
__device__ __forceinline__ float wredsum(float x) {
#pragma unroll
  for (int d = 32; d >= 1; d >>= 1) x += __shfl_xor(x, d);
  return x;
}
__device__ __forceinline__ float wredmax(float x) {
#pragma unroll
  for (int d = 32; d >= 1; d >>= 1) x = fmaxf(x, __shfl_xor(x, d));
  return x;
}
__device__ __forceinline__ void gload16(const void* g, void* l) {
  __builtin_amdgcn_global_load_lds(
      (const __attribute__((address_space(1))) unsigned*)g,
      (__attribute__((address_space(3))) unsigned*)l, 16, 0, 0);
}

// ============ 128x128-tile GEMM, BK=32, XOR-swizzled LDS (m97-style) ======
// Fused epilogue: optional per-head src/dst projections (Wh . a) via 16-lane
// shuffle reduce + atomicAdd into sdv (must be pre-zeroed).
__global__ __launch_bounds__(256) void gemm128(
    const unsigned short* __restrict__ A, const unsigned short* __restrict__ Bt,
    int M, int N, int K, unsigned short* __restrict__ Cb,
    const float* __restrict__ avec, float* __restrict__ sdv, int FO) {
  __shared__ __align__(16) unsigned short As[128 * 32];
  __shared__ __align__(16) unsigned short Bs[128 * 32];
  const int t = threadIdx.x, lane = t & 63, w = t >> 6;
  const int wr = w >> 1, wc = w & 1;
  const int n0 = blockIdx.x * 128, m0 = blockIdx.y * 128;
  floatx4 acc[4][4] = {};
  const int arow = t >> 2;                          // 0..63
  const int schunk = (t & 3) ^ ((arow >> 1) & 3);   // pre-swizzled src chunk

  for (int kt = 0; kt < K; kt += 32) {
    __syncthreads();
    gload16(A + (size_t)(m0 + arow) * K + kt + schunk * 8, &As[t * 8]);
    gload16(A + (size_t)(m0 + 64 + arow) * K + kt + schunk * 8, &As[(256 + t) * 8]);
    gload16(Bt + (size_t)(n0 + arow) * K + kt + schunk * 8, &Bs[t * 8]);
    gload16(Bt + (size_t)(n0 + 64 + arow) * K + kt + schunk * 8, &Bs[(256 + t) * 8]);
    __syncthreads();
    short8 af[4], bfr[4];
    const int koff = lane >> 4;
#pragma unroll
    for (int m = 0; m < 4; ++m) {
      const int r = wr * 64 + (lane & 15) + m * 16;
      af[m] = *(const short8*)&As[r * 32 + ((koff ^ ((r >> 1) & 3)) << 3)];
    }
#pragma unroll
    for (int n = 0; n < 4; ++n) {
      const int r = wc * 64 + (lane & 15) + n * 16;
      bfr[n] = *(const short8*)&Bs[r * 32 + ((koff ^ ((r >> 1) & 3)) << 3)];
    }
#pragma unroll
    for (int m = 0; m < 4; ++m)
#pragma unroll
      for (int n = 0; n < 4; ++n)
        acc[m][n] = __builtin_amdgcn_mfma_f32_16x16x32_bf16(af[m], bfr[n], acc[m][n], 0, 0, 0);
  }

  const int rb = m0 + wr * 64 + (lane >> 4) * 4;
  const int cb = n0 + wc * 64 + (lane & 15);
#pragma unroll
  for (int m = 0; m < 4; ++m)
#pragma unroll
    for (int n = 0; n < 4; ++n) {
      const int col = cb + n * 16;
#pragma unroll
      for (int r = 0; r < 4; ++r) {
        const int row = rb + m * 16 + r;
        Cb[(size_t)row * N + col] = f2bf(acc[m][n][r]);
      }
    }

  if (avec) {  // fused src/dst projections
    const int h = n0 / FO;       // block lies within one head (128 | FO)
    const int cw0 = cb - h * FO; // col-in-head for n=0
    float as_[4], ad_[4];
#pragma unroll
    for (int n = 0; n < 4; ++n) {
      as_[n] = avec[h * 2 * FO + cw0 + n * 16];
      ad_[n] = avec[h * 2 * FO + FO + cw0 + n * 16];
    }
#pragma unroll
    for (int m = 0; m < 4; ++m)
#pragma unroll
      for (int r = 0; r < 4; ++r) {
        float sp = 0.f, dp = 0.f;
#pragma unroll
        for (int n = 0; n < 4; ++n) {
          sp += acc[m][n][r] * as_[n];
          dp += acc[m][n][r] * ad_[n];
        }
#pragma unroll
        for (int d = 1; d < 16; d <<= 1) {
          sp += __shfl_xor(sp, d);
          dp += __shfl_xor(dp, d);
        }
        if ((lane & 15) == 0) {
          const int row = rb + m * 16 + r;
          atomicAdd(&sdv[row * 8 + h], sp);
          atomicAdd(&sdv[row * 8 + 4 + h], dp);
        }
      }
  }
}

// ================= 64x64-tile GEMM, BK=64, XOR-swizzled LDS ===============
__device__ __forceinline__ void stage64(const unsigned short* __restrict__ G,
                                        unsigned short* lds, int row0, int K,
                                        int kt, int t) {
  const int l0 = t, l1 = t + 256;
  const int r0 = l0 >> 3, c0 = l0 & 7;
  const int r1 = l1 >> 3, c1 = l1 & 7;
  gload16(G + (size_t)(row0 + r0) * K + kt + ((c0 ^ (r0 & 7)) << 3), &lds[l0 * 8]);
  gload16(G + (size_t)(row0 + r1) * K + kt + ((c1 ^ (r1 & 7)) << 3), &lds[l1 * 8]);
}
__device__ __forceinline__ short8 frag64(const unsigned short* lds, int r, int c) {
  return *(const short8*)&lds[r * 64 + ((c ^ (r & 7)) << 3)];
}

// EP: 4 = relu(acc+bias[col]) -> bf16 (decoder layer 1)
template <int EP>
__global__ __launch_bounds__(256) void gemm64(
    const unsigned short* __restrict__ A, const unsigned short* __restrict__ Bt,
    int M, int N, int K, unsigned short* __restrict__ Cb,
    const float* __restrict__ bias) {
  __shared__ __align__(16) unsigned short As[64 * 64];
  __shared__ __align__(16) unsigned short Bs[64 * 64];
  const int t = threadIdx.x, lane = t & 63, w = t >> 6;
  const int wr = w >> 1, wc = w & 1;
  const int n0 = blockIdx.x * 64, m0 = blockIdx.y * 64;
  floatx4 acc[2][2] = {};

  for (int kt = 0; kt < K; kt += 64) {
    __syncthreads();
    stage64(A, As, m0, K, kt, t);
    stage64(Bt, Bs, n0, K, kt, t);
    __syncthreads();
    short8 af[2][2], bfv[2][2];
#pragma unroll
    for (int m = 0; m < 2; ++m) {
      const int ra = wr * 32 + (lane & 15) + m * 16;
#pragma unroll
      for (int kk = 0; kk < 2; ++kk)
        af[m][kk] = frag64(As, ra, (lane >> 4) + kk * 4);
    }
#pragma unroll
    for (int n = 0; n < 2; ++n) {
      const int rb = wc * 32 + (lane & 15) + n * 16;
#pragma unroll
      for (int kk = 0; kk < 2; ++kk)
        bfv[n][kk] = frag64(Bs, rb, (lane >> 4) + kk * 4);
    }
#pragma unroll
    for (int kk = 0; kk < 2; ++kk)
#pragma unroll
      for (int m = 0; m < 2; ++m)
#pragma unroll
        for (int n = 0; n < 2; ++n)
          acc[m][n] = __builtin_amdgcn_mfma_f32_16x16x32_bf16(af[m][kk], bfv[n][kk], acc[m][n], 0, 0, 0);
  }

  const int rb = m0 + wr * 32 + (lane >> 4) * 4;
  const int cb = n0 + wc * 32 + (lane & 15);
#pragma unroll
  for (int m = 0; m < 2; ++m)
#pragma unroll
    for (int n = 0; n < 2; ++n) {
      const int col = cb + n * 16;
#pragma unroll
      for (int r = 0; r < 4; ++r) {
        const int row = rb + m * 16 + r;
        float v = acc[m][n][r];
        if (EP == 4) { v += bias[col]; v = v > 0.f ? v : 0.f; }
        Cb[(size_t)row * N + col] = f2bf(v);
      }
    }
}

// C = relu(elu(A1@B1t) + A2@B2t).  EP0: bf16 store (merged).
// EP1: f32 store split — rows<4096 -> Cfo, rows>=4096 -> Cfa.
template <int EP>
__global__ __launch_bounds__(256) void gemm64dual(
    const unsigned short* __restrict__ A1, const unsigned short* __restrict__ B1t, int K1,
    const unsigned short* __restrict__ A2, const unsigned short* __restrict__ B2t, int K2,
    int N, unsigned short* __restrict__ Cb,
    float* __restrict__ Cfo, float* __restrict__ Cfa) {
  __shared__ __align__(16) unsigned short As[64 * 64];
  __shared__ __align__(16) unsigned short Bs[64 * 64];
  const int t = threadIdx.x, lane = t & 63, w = t >> 6;
  const int wr = w >> 1, wc = w & 1;
  const int n0 = blockIdx.x * 64, m0 = blockIdx.y * 64;
  floatx4 acc[2][2] = {};

#pragma unroll 1
  for (int pass = 0; pass < 2; ++pass) {
    const unsigned short* A = pass ? A2 : A1;
    const unsigned short* Bt = pass ? B2t : B1t;
    const int K = pass ? K2 : K1;
    for (int kt = 0; kt < K; kt += 64) {
      __syncthreads();
      stage64(A, As, m0, K, kt, t);
      stage64(Bt, Bs, n0, K, kt, t);
      __syncthreads();
      short8 af[2][2], bfv[2][2];
#pragma unroll
      for (int m = 0; m < 2; ++m) {
        const int ra = wr * 32 + (lane & 15) + m * 16;
#pragma unroll
        for (int kk = 0; kk < 2; ++kk)
          af[m][kk] = frag64(As, ra, (lane >> 4) + kk * 4);
      }
#pragma unroll
      for (int n = 0; n < 2; ++n) {
        const int rb = wc * 32 + (lane & 15) + n * 16;
#pragma unroll
        for (int kk = 0; kk < 2; ++kk)
          bfv[n][kk] = frag64(Bs, rb, (lane >> 4) + kk * 4);
      }
#pragma unroll
      for (int kk = 0; kk < 2; ++kk)
#pragma unroll
        for (int m = 0; m < 2; ++m)
#pragma unroll
          for (int n = 0; n < 2; ++n)
            acc[m][n] = __builtin_amdgcn_mfma_f32_16x16x32_bf16(af[m][kk], bfv[n][kk], acc[m][n], 0, 0, 0);
    }
    if (pass == 0) {
#pragma unroll
      for (int m = 0; m < 2; ++m)
#pragma unroll
        for (int n = 0; n < 2; ++n)
#pragma unroll
          for (int r = 0; r < 4; ++r) {
            float v = acc[m][n][r];
            acc[m][n][r] = v > 0.f ? v : expm1f(v);
          }
    }
  }

  const int rb = m0 + wr * 32 + (lane >> 4) * 4;
  const int cb = n0 + wc * 32 + (lane & 15);
#pragma unroll
  for (int m = 0; m < 2; ++m)
#pragma unroll
    for (int n = 0; n < 2; ++n) {
      const int col = cb + n * 16;
#pragma unroll
      for (int r = 0; r < 4; ++r) {
        const int row = rb + m * 16 + r;
        float v = acc[m][n][r];
        v = v > 0.f ? v : 0.f;
        if (EP == 0) {
          Cb[(size_t)row * N + col] = f2bf(v);
        } else {
          float* bb = (row < 4096) ? Cfo : Cfa;
          bb[(size_t)(row & 4095) * N + col] = v;
        }
      }
    }
}

// ---------------- mask scatter + sd zero ---------------------------------
__global__ __launch_bounds__(256) void scatter_kernel(
    const int* __restrict__ ei, unsigned long long* __restrict__ mb,
    float* __restrict__ sd1, float* __restrict__ sd2) {
  int b = blockIdx.x;
  if (b < 512) {
    int e = b * 256 + threadIdx.x;
    int r = ei[e], c = ei[N_EDGES + e];
    atomicOr(&mb[(size_t)r * 64 + (c >> 6)], 1ull << (c & 63));
  } else {  // zero sd1 (65536 floats) then sd2
    int z = (b - 512) * 256 + threadIdx.x;
    if (z < 65536) sd1[z] = 0.f;
    else sd2[z - 65536] = 0.f;
  }
}

// ---------------- CSR build: count / scan / fill (deterministic) ----------
__global__ __launch_bounds__(256) void csr_count(
    const unsigned long long* __restrict__ mb, int* __restrict__ rcnt) {
  int r = blockIdx.x * 256 + threadIdx.x;  // 0..4095
  int c = 0;
#pragma unroll 8
  for (int w = 0; w < 64; ++w) c += __popcll(mb[(size_t)r * 64 + w]);
  rcnt[r] = c;
}

__global__ __launch_bounds__(64) void csr_scan(
    const int* __restrict__ rcnt, int* __restrict__ rbase) {
  int l = threadIdx.x;  // 0..63, each owns 64 rows
  int s = 0;
  for (int k = 0; k < 64; ++k) s += rcnt[l * 64 + k];
  int pre = s;
#pragma unroll
  for (int d = 1; d < 64; d <<= 1) {
    int v = __shfl_up(pre, d);
    if (l >= d) pre += v;
  }
  pre -= s;  // exclusive prefix of this lane's chunk
  int run = pre;
  for (int k = 0; k < 64; ++k) {
    rbase[l * 64 + k] = run;
    run += rcnt[l * 64 + k];
  }
}

__global__ __launch_bounds__(64) void csr_fill(
    const unsigned long long* __restrict__ mb, const int* __restrict__ rbase,
    unsigned short* __restrict__ nbrg) {
  int r = blockIdx.x, t = threadIdx.x;
  unsigned long long wb = mb[(size_t)r * 64 + t];
  int pc = __popcll(wb);
  int inc = pc;
#pragma unroll
  for (int d = 1; d < 64; d <<= 1) {
    int v = __shfl_up(inc, d);
    if (t >= d) inc += v;
  }
  int off = rbase[r] + inc - pc;
  while (wb) {
    int b = __builtin_ctzll(wb);
    nbrg[off++] = (unsigned short)(t * 64 + b);
    wb &= wb - 1;
  }
}

// ---------------- weight pack: tiled f32->bf16 transposes + x casts -------
__global__ __launch_bounds__(256) void pack2_kernel(
    const float* W1, const float* lin1, const float* res1, const float* W2,
    const float* lin2, const float* res2, const float* dec1,
    const float* xo, const float* xa,
    unsigned short* dW1, unsigned short* dlin1, unsigned short* dres1,
    unsigned short* dW2, unsigned short* dlin2, unsigned short* dres2,
    unsigned short* ddec1, unsigned short* x16) {
  const int b = blockIdx.x, t = threadIdx.x;
  if (b >= 1248) {  // x_o / x_a f32 -> bf16 into merged [8192][512]
    int ib = b - 1248;
    const float* src = (ib < 512) ? xo : xa;
    unsigned short* dst = x16 + ((ib < 512) ? 0 : (size_t)4096 * 512);
    size_t base = (size_t)(ib & 511) * 4096;
#pragma unroll
    for (int q = 0; q < 4; ++q) {
      size_t o = base + q * 1024 + t * 4;
      float4 v = *(const float4*)&src[o];
      ushort4 u = {f2bf(v.x), f2bf(v.y), f2bf(v.z), f2bf(v.w)};
      *(ushort4*)&dst[o] = u;
    }
    return;
  }
  const float* src; unsigned short* dst; int K, F, nFt, tb;
  if (b < 512)       { int h = b >> 7;        src = W1 + h * 131072; dst = dW1 + h * 131072; K = 512;  F = 256; nFt = 8;  tb = b & 127; }
  else if (b < 768)  {                        src = lin1;            dst = dlin1;            K = 1024; F = 256; nFt = 8;  tb = b - 512; }
  else if (b < 896)  {                        src = res1;            dst = dres1;            K = 512;  F = 256; nFt = 8;  tb = b - 768; }
  else if (b < 1024) { int h = (b - 896) >> 5; src = W2 + h * 32768; dst = dW2 + h * 32768;  K = 256;  F = 128; nFt = 4;  tb = (b - 896) & 31; }
  else if (b < 1088) {                        src = lin2;            dst = dlin2;            K = 512;  F = 128; nFt = 4;  tb = b - 1024; }
  else if (b < 1120) {                        src = res2;            dst = dres2;            K = 256;  F = 128; nFt = 4;  tb = b - 1088; }
  else               {                        src = dec1;            dst = ddec1;            K = 256;  F = 512; nFt = 16; tb = b - 1120; }
  const int k0 = (tb / nFt) * 32, f0 = (tb % nFt) * 32;
  __shared__ float tile[32][33];
  {
    int r = t >> 3, c4 = (t & 7) * 4;
    float4 v = *(const float4*)&src[(size_t)(k0 + r) * F + f0 + c4];
    tile[r][c4] = v.x; tile[r][c4 + 1] = v.y; tile[r][c4 + 2] = v.z; tile[r][c4 + 3] = v.w;
  }
  __syncthreads();
  {
    int f = t >> 3, k4 = (t & 7) * 4;
    ushort4 u;
    u.x = f2bf(tile[k4 + 0][f]); u.y = f2bf(tile[k4 + 1][f]);
    u.z = f2bf(tile[k4 + 2][f]); u.w = f2bf(tile[k4 + 3][f]);
    *(ushort4*)&dst[(size_t)(f0 + f) * K + k0 + k4] = u;
  }
}

// ------- sparse attention, XCD-local (combo = head x encode = bid&7) ------
// One wave per row per combo; no block barriers (wave-private LDS only).
// combo = bid & 7 -> under round-robin dispatch each XCD sees one combo, so
// its gather working set is one (head,encode) slice (1-2 MB, L2-resident).
template <int FO>
__global__ __launch_bounds__(256) void attn2_kernel(
    const int* __restrict__ rcnt, const int* __restrict__ rbase,
    const unsigned short* __restrict__ nbrg, const float* __restrict__ sd,
    const unsigned short* __restrict__ Wh, unsigned short* __restrict__ outp) {
  constexpr int E = FO / 64;
  constexpr int W = 4 * FO;
  constexpr int CAP = 512;  // multiple of 8
  __shared__ __align__(16) unsigned short nb[4][CAP + 8];
  __shared__ __align__(16) float wg[4][CAP + 8];
  const int bid = blockIdx.x;
  const int combo = bid & 7, chunk = bid >> 3;
  const int h = combo & 3, e = combo >> 2;
  const int t = threadIdx.x, lane = t & 63, wv = t >> 6;
  const int r = chunk * 4 + wv;        // mask row 0..4095
  const int i = e * 4096 + r;          // Wh row
  const int jb = e * 4096;             // neighbor row offset
  const int cnt = rcnt[r], boff = rbase[r];
  const float src_i = sd[(size_t)i * 8 + h];
  float acc[E] = {};
  float inv = 1.f;

  if (cnt > 0) {
    // pass 1: row max; also cache neighbor ids into wave-private LDS
    float m = -1e30f;
    for (int nn = lane; nn < cnt; nn += 64) {
      int j = nbrg[boff + nn];
      if (nn < CAP) nb[wv][nn] = (unsigned short)j;
      float x = src_i + sd[(size_t)(jb + j) * 8 + 4 + h];
      m = fmaxf(m, x > 0.f ? x : 0.2f * x);
    }
    m = wredmax(m);
    // pass 2: unnormalized weights -> LDS, sum
    float ssum = 0.f;
    for (int nn = lane; nn < cnt; nn += 64) {
      int j = nbrg[boff + nn];
      float x = src_i + sd[(size_t)(jb + j) * 8 + 4 + h];
      float ee = x > 0.f ? x : 0.2f * x;
      float g = __expf(ee - m);
      if (nn < CAP) wg[wv][nn] = g;
      ssum += g;
    }
    ssum = wredsum(ssum);
    inv = 1.f / ssum;
    const int limc = cnt < CAP ? cnt : CAP;
    if (lane < 8) { nb[wv][limc + lane] = 0; wg[wv][limc + lane] = 0.f; }
    // pass 3: 8-wide unrolled gather (wave-private LDS; no barriers needed)
    const int ngroups = (limc + 7) >> 3;
    for (int g = 0; g < ngroups; ++g) {
      const int nn = g * 8;
      ushort4 ja = *(const ushort4*)&nb[wv][nn];
      ushort4 jb4 = *(const ushort4*)&nb[wv][nn + 4];
      float4 wa = *(const float4*)&wg[wv][nn];
      float4 wb4 = *(const float4*)&wg[wv][nn + 4];
      const int js[8] = {ja.x, ja.y, ja.z, ja.w, jb4.x, jb4.y, jb4.z, jb4.w};
      const float ws[8] = {wa.x, wa.y, wa.z, wa.w, wb4.x, wb4.y, wb4.z, wb4.w};
      if constexpr (E == 4) {
        uint2 rv[8];
#pragma unroll
        for (int q = 0; q < 8; ++q)
          rv[q] = *(const uint2*)(Wh + (size_t)(jb + js[q]) * W + h * FO + lane * 4);
#pragma unroll
        for (int q = 0; q < 8; ++q) {
          acc[0] += ws[q] * bf2f((unsigned short)(rv[q].x & 0xffff));
          acc[1] += ws[q] * bf2f((unsigned short)(rv[q].x >> 16));
          acc[2] += ws[q] * bf2f((unsigned short)(rv[q].y & 0xffff));
          acc[3] += ws[q] * bf2f((unsigned short)(rv[q].y >> 16));
        }
      } else {
        unsigned rv[8];
#pragma unroll
        for (int q = 0; q < 8; ++q)
          rv[q] = *(const unsigned*)(Wh + (size_t)(jb + js[q]) * W + h * FO + lane * 2);
#pragma unroll
        for (int q = 0; q < 8; ++q) {
          acc[0] += ws[q] * bf2f((unsigned short)(rv[q] & 0xffff));
          acc[1] += ws[q] * bf2f((unsigned short)(rv[q] >> 16));
        }
      }
    }
    // tail beyond CAP: recompute weights inline (unreachable for this input)
    for (int nn = CAP; nn < cnt; ++nn) {
      int j = nbrg[boff + nn];
      float x = src_i + sd[(size_t)(jb + j) * 8 + 4 + h];
      float ee = x > 0.f ? x : 0.2f * x;
      float g = __expf(ee - m);
      const unsigned short* p = Wh + (size_t)(jb + j) * W + h * FO + lane * E;
#pragma unroll
      for (int q = 0; q < E; ++q) acc[q] += g * bf2f(p[q]);
    }
  } else {  // all-masked row: softmax over NEG row is uniform 1/N
    const float wgu = 1.f / 4096.f;
    for (int j = 0; j < N_NODES; ++j) {
      const unsigned short* p = Wh + (size_t)(jb + j) * W + h * FO + lane * E;
#pragma unroll
      for (int q = 0; q < E; ++q) acc[q] += wgu * bf2f(p[q]);
    }
  }
  unsigned short* op = outp + (size_t)i * W + h * FO + lane * E;
#pragma unroll
  for (int q = 0; q < E; ++q) {
    float v = acc[q] * inv;
    op[q] = f2bf(v > 0.f ? v : expm1f(v));
  }
}

// ---------------- column sums of x2 (for mean) ---------------------------
__global__ __launch_bounds__(128) void colsum_kernel(
    const float* __restrict__ x2o, const float* __restrict__ x2a,
    float* __restrict__ small) {
  int b = blockIdx.x, f = threadIdx.x;
  const float* x = (b < 64) ? x2o : x2a;
  float* s = (b < 64) ? small : (small + 128);
  int r0 = (b & 63) * 64;
  float acc = 0.f;
  for (int r = 0; r < 64; ++r) acc += x[(size_t)(r0 + r) * 128 + f];
  atomicAdd(&s[f], acc);
}

// ---------------- tiny head math (single block) --------------------------
__global__ __launch_bounds__(128) void finalize_kernel(
    float* __restrict__ small, const float* __restrict__ mlp1_w,
    const float* __restrict__ mlp1_b, const float* __restrict__ disc_w,
    const float* __restrict__ adv_w, const float* __restrict__ adv_b) {
  __shared__ float so[128], sa[128], ho[128], ha[128];
  int f = threadIdx.x;
  so[f] = 1.f / (1.f + __expf(-small[f] * (1.f / 4096.f)));
  sa[f] = 1.f / (1.f + __expf(-small[128 + f] * (1.f / 4096.f)));
  __syncthreads();
  float aco = mlp1_b[f], aca = mlp1_b[f];
  for (int c = 0; c < 128; ++c) {
    aco += so[c] * mlp1_w[c * 128 + f];
    aca += sa[c] * mlp1_w[c * 128 + f];
  }
  ho[f] = aco;
  ha[f] = aca;
  __syncthreads();
  float vo = 0.f, va = 0.f, ar = 0.f;
  for (int c = 0; c < 128; ++c) {
    vo += disc_w[f * 128 + c] * ho[c];
    va += disc_w[f * 128 + c] * ha[c];
    ar += adv_w[f * 128 + c];
  }
  small[256 + f] = vo;
  small[384 + f] = va;
  small[512 + f] = ar;
  if (f == 0) {
    float b = 0.f;
    for (int c = 0; c < 128; ++c) b += adv_b[c];
    small[640] = b;
  }
}

// ---------------- per-node disc / adv outputs ----------------------------
__global__ __launch_bounds__(256) void pernode_kernel(
    const float* __restrict__ x2o, const float* __restrict__ x2a,
    const float* __restrict__ small, const float* __restrict__ disc_b,
    float* __restrict__ out) {
  const float* v_os = small + 256;
  const float* v_a = small + 384;
  const float* adv_rs = small + 512;
  int lane = threadIdx.x & 63, wv = threadIdx.x >> 6;
  int i = blockIdx.x * 4 + wv;
  float2 xo = *(const float2*)&x2o[(size_t)i * 128 + lane * 2];
  float2 xa = *(const float2*)&x2a[(size_t)i * 128 + lane * 2];
  float2 vo = *(const float2*)&v_os[lane * 2];
  float2 va = *(const float2*)&v_a[lane * 2];
  float2 ar = *(const float2*)&adv_rs[lane * 2];
  float poo = wredsum(xo.x * vo.x + xo.y * vo.y);
  float pao = wredsum(xa.x * vo.x + xa.y * vo.y);
  float paa = wredsum(xa.x * va.x + xa.y * va.y);
  float poa = wredsum(xo.x * va.x + xo.y * va.y);
  float pov = wredsum(xo.x * ar.x + xo.y * ar.y);
  float pav = wredsum(xa.x * ar.x + xa.y * ar.y);
  if (lane == 0) {
    float db = disc_b[0], bv = small[640];
    out[4096 + 2 * i] = poo + db;
    out[4096 + 2 * i + 1] = pao + db;
    out[12288 + 2 * i] = paa + db;
    out[12288 + 2 * i + 1] = poa + db;
    out[544768 + i] = pov + bv;
    out[548864 + i] = pav + bv;
  }
}

// ---------------- decoder gather / final dot -----------------------------
__global__ __launch_bounds__(256) void gather_kernel(
    const float* __restrict__ x2o, const int* __restrict__ idx,
    unsigned short* __restrict__ z) {
  int i = blockIdx.x, c = threadIdx.x;
  int s = (c < 128) ? idx[i] : idx[4096 + i];
  z[(size_t)i * 256 + c] = f2bf(x2o[(size_t)s * 128 + (c & 127)]);
}

__global__ __launch_bounds__(256) void dec2_kernel(
    const unsigned short* __restrict__ hdec, const float* __restrict__ w2,
    const float* __restrict__ b2, float* __restrict__ out) {
  int lane = threadIdx.x & 63, wv = threadIdx.x >> 6;
  int i = blockIdx.x * 4 + wv;
  float s = 0.f;
#pragma unroll
  for (int q = 0; q < 8; ++q) {
    int f = lane + q * 64;
    s += bf2f(hdec[(size_t)i * 512 + f]) * w2[f];
  }
  s = wredsum(s);
  if (lane == 0) {
    float v = s + b2[0];
    out[552960 + i] = v;           // log1
    out[i] = 1.f / (1.f + __expf(-v));  // log
  }
}

// ---------------- host orchestration -------------------------------------
extern "C" void kernel_launch(void* const* d_in, const int* in_sizes, int n_in,
                              void* d_out, int out_size, void* d_ws, size_t ws_size,
                              hipStream_t stream) {
  const float* x_o = (const float*)d_in[0];
  const float* x_a = (const float*)d_in[1];
  const int* ei = (const int*)d_in[2];
  const int* idx = (const int*)d_in[3];
  const float* W1 = (const float*)d_in[4];
  const float* a1 = (const float*)d_in[5];
  const float* lin1 = (const float*)d_in[6];
  const float* res1 = (const float*)d_in[7];
  const float* W2 = (const float*)d_in[8];
  const float* a2 = (const float*)d_in[9];
  const float* lin2 = (const float*)d_in[10];
  const float* res2 = (const float*)d_in[11];
  const float* mlp1_w = (const float*)d_in[12];
  const float* mlp1_b = (const float*)d_in[13];
  const float* disc_w = (const float*)d_in[14];
  const float* disc_b = (const float*)d_in[15];
  const float* dec1_w = (const float*)d_in[16];
  const float* dec1_b = (const float*)d_in[17];
  const float* dec2_w = (const float*)d_in[18];
  const float* dec2_b = (const float*)d_in[19];
  const float* adv_w = (const float*)d_in[20];
  const float* adv_b = (const float*)d_in[21];
  float* out = (float*)d_out;

  char* w = (char*)d_ws;
  size_t off = 0;
  auto alloc = [&](size_t b) {
    char* p = w + off;
    off += (b + 255) & ~(size_t)255;
    return p;
  };
  unsigned long long* mb = (unsigned long long*)alloc((size_t)4096 * 64 * 8);
  unsigned short* x16 = (unsigned short*)alloc((size_t)8192 * 512 * 2);
  unsigned short* Wh1 = (unsigned short*)alloc((size_t)8192 * 1024 * 2);
  unsigned short* ho1 = (unsigned short*)alloc((size_t)8192 * 1024 * 2);
  unsigned short* h1 = (unsigned short*)alloc((size_t)8192 * 256 * 2);
  unsigned short* Wh2 = (unsigned short*)alloc((size_t)8192 * 512 * 2);
  unsigned short* ho2 = (unsigned short*)alloc((size_t)8192 * 512 * 2);
  float* x2a = (float*)alloc((size_t)4096 * 128 * 4);
  float* sd1 = (float*)alloc((size_t)8192 * 8 * 4);
  float* sd2 = (float*)alloc((size_t)8192 * 8 * 4);
  float* small = (float*)alloc(1024 * 4);
  int* rcnt = (int*)alloc(4096 * 4);
  int* rbase = (int*)alloc(4096 * 4);
  unsigned short* nbrg = (unsigned short*)alloc((size_t)(N_EDGES + 64) * 2);
  unsigned short* tW1 = (unsigned short*)alloc((size_t)524288 * 2);
  unsigned short* tlin1 = (unsigned short*)alloc((size_t)262144 * 2);
  unsigned short* tres1 = (unsigned short*)alloc((size_t)131072 * 2);
  unsigned short* tW2 = (unsigned short*)alloc((size_t)131072 * 2);
  unsigned short* tlin2 = (unsigned short*)alloc((size_t)65536 * 2);
  unsigned short* tres2 = (unsigned short*)alloc((size_t)32768 * 2);
  unsigned short* tdec1 = (unsigned short*)alloc((size_t)131072 * 2);
  unsigned short* z16 = (unsigned short*)alloc((size_t)4096 * 256 * 2);
  unsigned short* hdec = (unsigned short*)alloc((size_t)4096 * 512 * 2);

  hipMemsetAsync(mb, 0, (size_t)4096 * 64 * 8, stream);
  hipMemsetAsync(small, 0, 1024, stream);  // colsum accumulators
  scatter_kernel<<<1024, 256, 0, stream>>>(ei, mb, sd1, sd2);
  pack2_kernel<<<2272, 256, 0, stream>>>(W1, lin1, res1, W2, lin2, res2, dec1_w,
                                         x_o, x_a, tW1, tlin1, tres1, tW2,
                                         tlin2, tres2, tdec1, x16);
  csr_count<<<16, 256, 0, stream>>>(mb, rcnt);
  csr_scan<<<1, 64, 0, stream>>>(rcnt, rbase);
  csr_fill<<<4096, 64, 0, stream>>>(mb, rbase, nbrg);

  float* x2o_out = out + 20480;  // x2_o lives directly in d_out

  // ---- merged encode (rows 0..4095 = x_o, 4096..8191 = x_a) ----
  gemm128<<<dim3(8, 64), 256, 0, stream>>>(x16, tW1, 8192, 1024, 512, Wh1, a1, sd1, 256);
  attn2_kernel<256><<<8192, 256, 0, stream>>>(rcnt, rbase, nbrg, sd1, Wh1, ho1);
  gemm64dual<0><<<dim3(4, 128), 256, 0, stream>>>(ho1, tlin1, 1024, x16, tres1, 512, 256, h1, nullptr, nullptr);
  gemm128<<<dim3(4, 64), 256, 0, stream>>>(h1, tW2, 8192, 512, 256, Wh2, a2, sd2, 128);
  attn2_kernel<128><<<8192, 256, 0, stream>>>(rcnt, rbase, nbrg, sd2, Wh2, ho2);
  gemm64dual<1><<<dim3(2, 128), 256, 0, stream>>>(ho2, tlin2, 512, h1, tres2, 256, 128, nullptr, x2o_out, x2a);

  colsum_kernel<<<128, 128, 0, stream>>>(x2o_out, x2a, small);
  finalize_kernel<<<1, 128, 0, stream>>>(small, mlp1_w, mlp1_b, disc_w, adv_w, adv_b);
  pernode_kernel<<<1024, 256, 0, stream>>>(x2o_out, x2a, small, disc_b, out);
  gather_kernel<<<4096, 256, 0, stream>>>(x2o_out, idx, z16);
  gemm64<4><<<dim3(8, 64), 256, 0, stream>>>(z16, tdec1, 4096, 512, 256, hdec, dec1_b);
  dec2_kernel<<<1024, 256, 0, stream>>>(hdec, dec2_w, dec2_b, out);
}

// Round 9
// 216.652 us; speedup vs baseline: 1.0890x; 1.0599x over previous
//
#include <hip/hip_runtime.h>
#include <stdint.h>

#define N_NODES 4096
#define N_EDGES 131072

typedef __attribute__((ext_vector_type(8))) short short8;
typedef __attribute__((ext_vector_type(4))) float floatx4;

__device__ __forceinline__ float bf2f(unsigned short u) {
  union { unsigned u; float f; } v; v.u = ((unsigned)u) << 16; return v.f;
}
__device__ __forceinline__ unsigned short f2bf(float f) {
  union { float f; unsigned u; } v; v.f = f;
  unsigned r = 0x7FFFu + ((v.u >> 16) & 1u);
  return (unsigned short)((v.u + r) >> 16);
}
__device__ __forceinline__ float wredsum(float x) {
#pragma unroll
  for (int d = 32; d >= 1; d >>= 1) x += __shfl_xor(x, d);
  return x;
}
__device__ __forceinline__ float wredmax(float x) {
#pragma unroll
  for (int d = 32; d >= 1; d >>= 1) x = fmaxf(x, __shfl_xor(x, d));
  return x;
}
__device__ __forceinline__ void gload16(const void* g, void* l) {
  __builtin_amdgcn_global_load_lds(
      (const __attribute__((address_space(1))) unsigned*)g,
      (__attribute__((address_space(3))) unsigned*)l, 16, 0, 0);
}

// ============ 128x128-tile GEMM, BK=32, XOR-swizzled LDS (m97-style) ======
// Fused epilogue: optional per-head src/dst projections (Wh . a) via 16-lane
// shuffle reduce + atomicAdd into sdv (must be pre-zeroed).
__global__ __launch_bounds__(256) void gemm128(
    const unsigned short* __restrict__ A, const unsigned short* __restrict__ Bt,
    int M, int N, int K, unsigned short* __restrict__ Cb,
    const float* __restrict__ avec, float* __restrict__ sdv, int FO) {
  __shared__ __align__(16) unsigned short As[128 * 32];
  __shared__ __align__(16) unsigned short Bs[128 * 32];
  const int t = threadIdx.x, lane = t & 63, w = t >> 6;
  const int wr = w >> 1, wc = w & 1;
  const int n0 = blockIdx.x * 128, m0 = blockIdx.y * 128;
  floatx4 acc[4][4] = {};
  const int arow = t >> 2;                          // 0..63
  const int schunk = (t & 3) ^ ((arow >> 1) & 3);   // pre-swizzled src chunk

  for (int kt = 0; kt < K; kt += 32) {
    __syncthreads();
    gload16(A + (size_t)(m0 + arow) * K + kt + schunk * 8, &As[t * 8]);
    gload16(A + (size_t)(m0 + 64 + arow) * K + kt + schunk * 8, &As[(256 + t) * 8]);
    gload16(Bt + (size_t)(n0 + arow) * K + kt + schunk * 8, &Bs[t * 8]);
    gload16(Bt + (size_t)(n0 + 64 + arow) * K + kt + schunk * 8, &Bs[(256 + t) * 8]);
    __syncthreads();
    short8 af[4], bfr[4];
    const int koff = lane >> 4;
#pragma unroll
    for (int m = 0; m < 4; ++m) {
      const int r = wr * 64 + (lane & 15) + m * 16;
      af[m] = *(const short8*)&As[r * 32 + ((koff ^ ((r >> 1) & 3)) << 3)];
    }
#pragma unroll
    for (int n = 0; n < 4; ++n) {
      const int r = wc * 64 + (lane & 15) + n * 16;
      bfr[n] = *(const short8*)&Bs[r * 32 + ((koff ^ ((r >> 1) & 3)) << 3)];
    }
#pragma unroll
    for (int m = 0; m < 4; ++m)
#pragma unroll
      for (int n = 0; n < 4; ++n)
        acc[m][n] = __builtin_amdgcn_mfma_f32_16x16x32_bf16(af[m], bfr[n], acc[m][n], 0, 0, 0);
  }

  const int rb = m0 + wr * 64 + (lane >> 4) * 4;
  const int cb = n0 + wc * 64 + (lane & 15);
#pragma unroll
  for (int m = 0; m < 4; ++m)
#pragma unroll
    for (int n = 0; n < 4; ++n) {
      const int col = cb + n * 16;
#pragma unroll
      for (int r = 0; r < 4; ++r) {
        const int row = rb + m * 16 + r;
        Cb[(size_t)row * N + col] = f2bf(acc[m][n][r]);
      }
    }

  if (avec) {  // fused src/dst projections
    const int h = n0 / FO;       // block lies within one head (128 | FO)
    const int cw0 = cb - h * FO; // col-in-head for n=0
    float as_[4], ad_[4];
#pragma unroll
    for (int n = 0; n < 4; ++n) {
      as_[n] = avec[h * 2 * FO + cw0 + n * 16];
      ad_[n] = avec[h * 2 * FO + FO + cw0 + n * 16];
    }
#pragma unroll
    for (int m = 0; m < 4; ++m)
#pragma unroll
      for (int r = 0; r < 4; ++r) {
        float sp = 0.f, dp = 0.f;
#pragma unroll
        for (int n = 0; n < 4; ++n) {
          sp += acc[m][n][r] * as_[n];
          dp += acc[m][n][r] * ad_[n];
        }
#pragma unroll
        for (int d = 1; d < 16; d <<= 1) {
          sp += __shfl_xor(sp, d);
          dp += __shfl_xor(dp, d);
        }
        if ((lane & 15) == 0) {
          const int row = rb + m * 16 + r;
          atomicAdd(&sdv[row * 8 + h], sp);
          atomicAdd(&sdv[row * 8 + 4 + h], dp);
        }
      }
  }
}

// ================= 64x64-tile GEMM, BK=64, XOR-swizzled LDS ===============
__device__ __forceinline__ void stage64(const unsigned short* __restrict__ G,
                                        unsigned short* lds, int row0, int K,
                                        int kt, int t) {
  const int l0 = t, l1 = t + 256;
  const int r0 = l0 >> 3, c0 = l0 & 7;
  const int r1 = l1 >> 3, c1 = l1 & 7;
  gload16(G + (size_t)(row0 + r0) * K + kt + ((c0 ^ (r0 & 7)) << 3), &lds[l0 * 8]);
  gload16(G + (size_t)(row0 + r1) * K + kt + ((c1 ^ (r1 & 7)) << 3), &lds[l1 * 8]);
}
__device__ __forceinline__ short8 frag64(const unsigned short* lds, int r, int c) {
  return *(const short8*)&lds[r * 64 + ((c ^ (r & 7)) << 3)];
}

// EP: 4 = relu(acc+bias[col]) -> bf16 (decoder layer 1)
template <int EP>
__global__ __launch_bounds__(256) void gemm64(
    const unsigned short* __restrict__ A, const unsigned short* __restrict__ Bt,
    int M, int N, int K, unsigned short* __restrict__ Cb,
    const float* __restrict__ bias) {
  __shared__ __align__(16) unsigned short As[64 * 64];
  __shared__ __align__(16) unsigned short Bs[64 * 64];
  const int t = threadIdx.x, lane = t & 63, w = t >> 6;
  const int wr = w >> 1, wc = w & 1;
  const int n0 = blockIdx.x * 64, m0 = blockIdx.y * 64;
  floatx4 acc[2][2] = {};

  for (int kt = 0; kt < K; kt += 64) {
    __syncthreads();
    stage64(A, As, m0, K, kt, t);
    stage64(Bt, Bs, n0, K, kt, t);
    __syncthreads();
    short8 af[2][2], bfv[2][2];
#pragma unroll
    for (int m = 0; m < 2; ++m) {
      const int ra = wr * 32 + (lane & 15) + m * 16;
#pragma unroll
      for (int kk = 0; kk < 2; ++kk)
        af[m][kk] = frag64(As, ra, (lane >> 4) + kk * 4);
    }
#pragma unroll
    for (int n = 0; n < 2; ++n) {
      const int rb = wc * 32 + (lane & 15) + n * 16;
#pragma unroll
      for (int kk = 0; kk < 2; ++kk)
        bfv[n][kk] = frag64(Bs, rb, (lane >> 4) + kk * 4);
    }
#pragma unroll
    for (int kk = 0; kk < 2; ++kk)
#pragma unroll
      for (int m = 0; m < 2; ++m)
#pragma unroll
        for (int n = 0; n < 2; ++n)
          acc[m][n] = __builtin_amdgcn_mfma_f32_16x16x32_bf16(af[m][kk], bfv[n][kk], acc[m][n], 0, 0, 0);
  }

  const int rb = m0 + wr * 32 + (lane >> 4) * 4;
  const int cb = n0 + wc * 32 + (lane & 15);
#pragma unroll
  for (int m = 0; m < 2; ++m)
#pragma unroll
    for (int n = 0; n < 2; ++n) {
      const int col = cb + n * 16;
#pragma unroll
      for (int r = 0; r < 4; ++r) {
        const int row = rb + m * 16 + r;
        float v = acc[m][n][r];
        if (EP == 4) { v += bias[col]; v = v > 0.f ? v : 0.f; }
        Cb[(size_t)row * N + col] = f2bf(v);
      }
    }
}

// C = relu(elu(A1@B1t) + A2@B2t).  EP0: bf16 store (merged).
// EP1: f32 store split — rows<4096 -> Cfo, rows>=4096 -> Cfa.
template <int EP>
__global__ __launch_bounds__(256) void gemm64dual(
    const unsigned short* __restrict__ A1, const unsigned short* __restrict__ B1t, int K1,
    const unsigned short* __restrict__ A2, const unsigned short* __restrict__ B2t, int K2,
    int N, unsigned short* __restrict__ Cb,
    float* __restrict__ Cfo, float* __restrict__ Cfa) {
  __shared__ __align__(16) unsigned short As[64 * 64];
  __shared__ __align__(16) unsigned short Bs[64 * 64];
  const int t = threadIdx.x, lane = t & 63, w = t >> 6;
  const int wr = w >> 1, wc = w & 1;
  const int n0 = blockIdx.x * 64, m0 = blockIdx.y * 64;
  floatx4 acc[2][2] = {};

#pragma unroll 1
  for (int pass = 0; pass < 2; ++pass) {
    const unsigned short* A = pass ? A2 : A1;
    const unsigned short* Bt = pass ? B2t : B1t;
    const int K = pass ? K2 : K1;
    for (int kt = 0; kt < K; kt += 64) {
      __syncthreads();
      stage64(A, As, m0, K, kt, t);
      stage64(Bt, Bs, n0, K, kt, t);
      __syncthreads();
      short8 af[2][2], bfv[2][2];
#pragma unroll
      for (int m = 0; m < 2; ++m) {
        const int ra = wr * 32 + (lane & 15) + m * 16;
#pragma unroll
        for (int kk = 0; kk < 2; ++kk)
          af[m][kk] = frag64(As, ra, (lane >> 4) + kk * 4);
      }
#pragma unroll
      for (int n = 0; n < 2; ++n) {
        const int rb = wc * 32 + (lane & 15) + n * 16;
#pragma unroll
        for (int kk = 0; kk < 2; ++kk)
          bfv[n][kk] = frag64(Bs, rb, (lane >> 4) + kk * 4);
      }
#pragma unroll
      for (int kk = 0; kk < 2; ++kk)
#pragma unroll
        for (int m = 0; m < 2; ++m)
#pragma unroll
          for (int n = 0; n < 2; ++n)
            acc[m][n] = __builtin_amdgcn_mfma_f32_16x16x32_bf16(af[m][kk], bfv[n][kk], acc[m][n], 0, 0, 0);
    }
    if (pass == 0) {  // elu via hw exp (bf16-precision-safe)
#pragma unroll
      for (int m = 0; m < 2; ++m)
#pragma unroll
        for (int n = 0; n < 2; ++n)
#pragma unroll
          for (int r = 0; r < 4; ++r) {
            float v = acc[m][n][r];
            acc[m][n][r] = v > 0.f ? v : __expf(v) - 1.f;
          }
    }
  }

  const int rb = m0 + wr * 32 + (lane >> 4) * 4;
  const int cb = n0 + wc * 32 + (lane & 15);
#pragma unroll
  for (int m = 0; m < 2; ++m)
#pragma unroll
    for (int n = 0; n < 2; ++n) {
      const int col = cb + n * 16;
#pragma unroll
      for (int r = 0; r < 4; ++r) {
        const int row = rb + m * 16 + r;
        float v = acc[m][n][r];
        v = v > 0.f ? v : 0.f;
        if (EP == 0) {
          Cb[(size_t)row * N + col] = f2bf(v);
        } else {
          float* bb = (row < 4096) ? Cfo : Cfa;
          bb[(size_t)(row & 4095) * N + col] = v;
        }
      }
    }
}

// ---------------- mask scatter + sd zero ---------------------------------
__global__ __launch_bounds__(256) void scatter_kernel(
    const int* __restrict__ ei, unsigned long long* __restrict__ mb,
    float* __restrict__ sd1, float* __restrict__ sd2) {
  int b = blockIdx.x;
  if (b < 512) {
    int e = b * 256 + threadIdx.x;
    int r = ei[e], c = ei[N_EDGES + e];
    atomicOr(&mb[(size_t)r * 64 + (c >> 6)], 1ull << (c & 63));
  } else {  // zero sd1 (65536 floats) then sd2
    int z = (b - 512) * 256 + threadIdx.x;
    if (z < 65536) sd1[z] = 0.f;
    else sd2[z - 65536] = 0.f;
  }
}

// ---------------- CSR build: count / scan / fill (deterministic) ----------
__global__ __launch_bounds__(256) void csr_count(
    const unsigned long long* __restrict__ mb, int* __restrict__ rcnt) {
  int r = blockIdx.x * 256 + threadIdx.x;  // 0..4095
  int c = 0;
#pragma unroll 8
  for (int w = 0; w < 64; ++w) c += __popcll(mb[(size_t)r * 64 + w]);
  rcnt[r] = c;
}

__global__ __launch_bounds__(64) void csr_scan(
    const int* __restrict__ rcnt, int* __restrict__ rbase) {
  int l = threadIdx.x;  // 0..63, each owns 64 rows
  int s = 0;
  for (int k = 0; k < 64; ++k) s += rcnt[l * 64 + k];
  int pre = s;
#pragma unroll
  for (int d = 1; d < 64; d <<= 1) {
    int v = __shfl_up(pre, d);
    if (l >= d) pre += v;
  }
  pre -= s;  // exclusive prefix of this lane's chunk
  int run = pre;
  for (int k = 0; k < 64; ++k) {
    rbase[l * 64 + k] = run;
    run += rcnt[l * 64 + k];
  }
}

__global__ __launch_bounds__(256) void csr_fill(
    const unsigned long long* __restrict__ mb, const int* __restrict__ rbase,
    unsigned short* __restrict__ nbrg) {
  int r = blockIdx.x * 4 + (threadIdx.x >> 6);
  int t = threadIdx.x & 63;
  unsigned long long wb = mb[(size_t)r * 64 + t];
  int pc = __popcll(wb);
  int inc = pc;
#pragma unroll
  for (int d = 1; d < 64; d <<= 1) {
    int v = __shfl_up(inc, d);
    if (t >= d) inc += v;
  }
  int off = rbase[r] + inc - pc;
  while (wb) {
    int b = __builtin_ctzll(wb);
    nbrg[off++] = (unsigned short)(t * 64 + b);
    wb &= wb - 1;
  }
}

// ---------------- weight pack: tiled f32->bf16 transposes + x casts -------
__global__ __launch_bounds__(256) void pack2_kernel(
    const float* W1, const float* lin1, const float* res1, const float* W2,
    const float* lin2, const float* res2, const float* dec1,
    const float* xo, const float* xa,
    unsigned short* dW1, unsigned short* dlin1, unsigned short* dres1,
    unsigned short* dW2, unsigned short* dlin2, unsigned short* dres2,
    unsigned short* ddec1, unsigned short* x16) {
  const int b = blockIdx.x, t = threadIdx.x;
  if (b >= 1248) {  // x_o / x_a f32 -> bf16 into merged [8192][512]
    int ib = b - 1248;
    const float* src = (ib < 512) ? xo : xa;
    unsigned short* dst = x16 + ((ib < 512) ? 0 : (size_t)4096 * 512);
    size_t base = (size_t)(ib & 511) * 4096;
#pragma unroll
    for (int q = 0; q < 4; ++q) {
      size_t o = base + q * 1024 + t * 4;
      float4 v = *(const float4*)&src[o];
      ushort4 u = {f2bf(v.x), f2bf(v.y), f2bf(v.z), f2bf(v.w)};
      *(ushort4*)&dst[o] = u;
    }
    return;
  }
  const float* src; unsigned short* dst; int K, F, nFt, tb;
  if (b < 512)       { int h = b >> 7;        src = W1 + h * 131072; dst = dW1 + h * 131072; K = 512;  F = 256; nFt = 8;  tb = b & 127; }
  else if (b < 768)  {                        src = lin1;            dst = dlin1;            K = 1024; F = 256; nFt = 8;  tb = b - 512; }
  else if (b < 896)  {                        src = res1;            dst = dres1;            K = 512;  F = 256; nFt = 8;  tb = b - 768; }
  else if (b < 1024) { int h = (b - 896) >> 5; src = W2 + h * 32768; dst = dW2 + h * 32768;  K = 256;  F = 128; nFt = 4;  tb = (b - 896) & 31; }
  else if (b < 1088) {                        src = lin2;            dst = dlin2;            K = 512;  F = 128; nFt = 4;  tb = b - 1024; }
  else if (b < 1120) {                        src = res2;            dst = dres2;            K = 256;  F = 128; nFt = 4;  tb = b - 1088; }
  else               {                        src = dec1;            dst = ddec1;            K = 256;  F = 512; nFt = 16; tb = b - 1120; }
  const int k0 = (tb / nFt) * 32, f0 = (tb % nFt) * 32;
  __shared__ float tile[32][33];
  {
    int r = t >> 3, c4 = (t & 7) * 4;
    float4 v = *(const float4*)&src[(size_t)(k0 + r) * F + f0 + c4];
    tile[r][c4] = v.x; tile[r][c4 + 1] = v.y; tile[r][c4 + 2] = v.z; tile[r][c4 + 3] = v.w;
  }
  __syncthreads();
  {
    int f = t >> 3, k4 = (t & 7) * 4;
    ushort4 u;
    u.x = f2bf(tile[k4 + 0][f]); u.y = f2bf(tile[k4 + 1][f]);
    u.z = f2bf(tile[k4 + 2][f]); u.w = f2bf(tile[k4 + 3][f]);
    *(ushort4*)&dst[(size_t)(f0 + f) * K + k0 + k4] = u;
  }
}

// ------- sparse attention, XCD-local (combo = head x encode = bid&7) ------
// One wave per row per combo; wave-private LDS only, no barriers.
// Single-pass softmax when cnt<=64 (each lane owns one neighbor); pass 3
// uses readfirstlane so gather addresses are SGPR-based (scalar-unit math).
template <int FO>
__global__ __launch_bounds__(256) void attn2_kernel(
    const int* __restrict__ rcnt, const int* __restrict__ rbase,
    const unsigned short* __restrict__ nbrg, const float* __restrict__ sd,
    const unsigned short* __restrict__ Wh, unsigned short* __restrict__ outp) {
  constexpr int E = FO / 64;
  constexpr int W = 4 * FO;
  constexpr int CAP = 512;  // multiple of 8
  __shared__ __align__(16) unsigned short nb[4][CAP + 8];
  __shared__ __align__(16) float wg[4][CAP + 8];
  const int bid = blockIdx.x;
  const int combo = bid & 7, chunk = bid >> 3;
  const int h = combo & 3, e = combo >> 2;
  const int t = threadIdx.x, lane = t & 63, wv = t >> 6;
  const int r = chunk * 4 + wv;        // mask row 0..4095
  const int i = e * 4096 + r;          // Wh row
  const int jb = e * 4096;             // neighbor row offset
  const int cnt = rcnt[r], boff = rbase[r];
  const float src_i = sd[(size_t)i * 8 + h];
  float acc[E] = {};
  float inv = 1.f;

  if (cnt > 0) {
    const int limc = cnt < CAP ? cnt : CAP;
    if (cnt <= 64) {
      // single-pass softmax: each lane owns one neighbor
      int j = 0;
      float ee = -1e30f;
      if (lane < cnt) {
        j = nbrg[boff + lane];
        float x = src_i + sd[(size_t)(jb + j) * 8 + 4 + h];
        ee = x > 0.f ? x : 0.2f * x;
      }
      float m = wredmax(ee);
      float g = (lane < cnt) ? __expf(ee - m) : 0.f;
      nb[wv][lane] = (unsigned short)j;   // inactive lanes: j=0, weight 0
      wg[wv][lane] = g;
      inv = 1.f / wredsum(g);
    } else {
      // two-pass fallback (rare: cnt > 64)
      float m = -1e30f;
      for (int nn = lane; nn < cnt; nn += 64) {
        int j = nbrg[boff + nn];
        if (nn < CAP) nb[wv][nn] = (unsigned short)j;
        float x = src_i + sd[(size_t)(jb + j) * 8 + 4 + h];
        m = fmaxf(m, x > 0.f ? x : 0.2f * x);
      }
      m = wredmax(m);
      float ssum = 0.f;
      for (int nn = lane; nn < cnt; nn += 64) {
        int j = nbrg[boff + nn];
        float x = src_i + sd[(size_t)(jb + j) * 8 + 4 + h];
        float ee = x > 0.f ? x : 0.2f * x;
        float g = __expf(ee - m);
        if (nn < CAP) wg[wv][nn] = g;
        ssum += g;
      }
      ssum = wredsum(ssum);
      inv = 1.f / ssum;
      if (lane < 8) { nb[wv][limc + lane] = 0; wg[wv][limc + lane] = 0.f; }
      // tail beyond CAP: accumulate directly (weights recomputed)
      for (int nn = CAP; nn < cnt; ++nn) {
        int j = nbrg[boff + nn];
        float x = src_i + sd[(size_t)(jb + j) * 8 + 4 + h];
        float ee = x > 0.f ? x : 0.2f * x;
        float g = __expf(ee - m);
        const unsigned short* p = Wh + (size_t)(jb + j) * W + h * FO + lane * E;
#pragma unroll
        for (int q = 0; q < E; ++q) acc[q] += g * bf2f(p[q]);
      }
    }
    // pass 3: 8-wide unrolled gather; neighbor ids are wave-uniform -> SGPR
    const int ngroups = (limc + 7) >> 3;
    for (int g = 0; g < ngroups; ++g) {
      const int nn = g * 8;
      ushort4 ja = *(const ushort4*)&nb[wv][nn];
      ushort4 jb4 = *(const ushort4*)&nb[wv][nn + 4];
      float4 wa = *(const float4*)&wg[wv][nn];
      float4 wb4 = *(const float4*)&wg[wv][nn + 4];
      const int js[8] = {__builtin_amdgcn_readfirstlane((int)ja.x),
                         __builtin_amdgcn_readfirstlane((int)ja.y),
                         __builtin_amdgcn_readfirstlane((int)ja.z),
                         __builtin_amdgcn_readfirstlane((int)ja.w),
                         __builtin_amdgcn_readfirstlane((int)jb4.x),
                         __builtin_amdgcn_readfirstlane((int)jb4.y),
                         __builtin_amdgcn_readfirstlane((int)jb4.z),
                         __builtin_amdgcn_readfirstlane((int)jb4.w)};
      const float ws[8] = {wa.x, wa.y, wa.z, wa.w, wb4.x, wb4.y, wb4.z, wb4.w};
      if constexpr (E == 4) {
        uint2 rv[8];
#pragma unroll
        for (int q = 0; q < 8; ++q)
          rv[q] = *(const uint2*)(Wh + (size_t)(jb + js[q]) * W + h * FO + lane * 4);
#pragma unroll
        for (int q = 0; q < 8; ++q) {
          union { unsigned u; float f; } l0, h0, l1, h1;
          l0.u = rv[q].x << 16; h0.u = rv[q].x & 0xffff0000u;
          l1.u = rv[q].y << 16; h1.u = rv[q].y & 0xffff0000u;
          acc[0] += ws[q] * l0.f;
          acc[1] += ws[q] * h0.f;
          acc[2] += ws[q] * l1.f;
          acc[3] += ws[q] * h1.f;
        }
      } else {
        unsigned rv[8];
#pragma unroll
        for (int q = 0; q < 8; ++q)
          rv[q] = *(const unsigned*)(Wh + (size_t)(jb + js[q]) * W + h * FO + lane * 2);
#pragma unroll
        for (int q = 0; q < 8; ++q) {
          union { unsigned u; float f; } l0, h0;
          l0.u = rv[q] << 16; h0.u = rv[q] & 0xffff0000u;
          acc[0] += ws[q] * l0.f;
          acc[1] += ws[q] * h0.f;
        }
      }
    }
  } else {  // all-masked row: softmax over NEG row is uniform 1/N
    const float wgu = 1.f / 4096.f;
    for (int j = 0; j < N_NODES; ++j) {
      const unsigned short* p = Wh + (size_t)(jb + j) * W + h * FO + lane * E;
#pragma unroll
      for (int q = 0; q < E; ++q) acc[q] += wgu * bf2f(p[q]);
    }
  }
  unsigned short* op = outp + (size_t)i * W + h * FO + lane * E;
#pragma unroll
  for (int q = 0; q < E; ++q) {
    float v = acc[q] * inv;
    op[q] = f2bf(v > 0.f ? v : __expf(v) - 1.f);
  }
}

// ---------------- column sums of x2 (for mean) ---------------------------
__global__ __launch_bounds__(128) void colsum_kernel(
    const float* __restrict__ x2o, const float* __restrict__ x2a,
    float* __restrict__ small) {
  int b = blockIdx.x, f = threadIdx.x;
  const float* x = (b < 64) ? x2o : x2a;
  float* s = (b < 64) ? small : (small + 128);
  int r0 = (b & 63) * 64;
  float acc = 0.f;
  for (int r = 0; r < 64; ++r) acc += x[(size_t)(r0 + r) * 128 + f];
  atomicAdd(&s[f], acc);
}

// ---------------- tiny head math (single block) --------------------------
__global__ __launch_bounds__(128) void finalize_kernel(
    float* __restrict__ small, const float* __restrict__ mlp1_w,
    const float* __restrict__ mlp1_b, const float* __restrict__ disc_w,
    const float* __restrict__ adv_w, const float* __restrict__ adv_b) {
  __shared__ float so[128], sa[128], ho[128], ha[128];
  int f = threadIdx.x;
  so[f] = 1.f / (1.f + __expf(-small[f] * (1.f / 4096.f)));
  sa[f] = 1.f / (1.f + __expf(-small[128 + f] * (1.f / 4096.f)));
  __syncthreads();
  float aco = mlp1_b[f], aca = mlp1_b[f];
  for (int c = 0; c < 128; ++c) {
    aco += so[c] * mlp1_w[c * 128 + f];
    aca += sa[c] * mlp1_w[c * 128 + f];
  }
  ho[f] = aco;
  ha[f] = aca;
  __syncthreads();
  float vo = 0.f, va = 0.f, ar = 0.f;
  for (int c = 0; c < 128; ++c) {
    vo += disc_w[f * 128 + c] * ho[c];
    va += disc_w[f * 128 + c] * ha[c];
    ar += adv_w[f * 128 + c];
  }
  small[256 + f] = vo;
  small[384 + f] = va;
  small[512 + f] = ar;
  if (f == 0) {
    float b = 0.f;
    for (int c = 0; c < 128; ++c) b += adv_b[c];
    small[640] = b;
  }
}

// ---------------- per-node disc / adv outputs ----------------------------
__global__ __launch_bounds__(256) void pernode_kernel(
    const float* __restrict__ x2o, const float* __restrict__ x2a,
    const float* __restrict__ small, const float* __restrict__ disc_b,
    float* __restrict__ out) {
  const float* v_os = small + 256;
  const float* v_a = small + 384;
  const float* adv_rs = small + 512;
  int lane = threadIdx.x & 63, wv = threadIdx.x >> 6;
  int i = blockIdx.x * 4 + wv;
  float2 xo = *(const float2*)&x2o[(size_t)i * 128 + lane * 2];
  float2 xa = *(const float2*)&x2a[(size_t)i * 128 + lane * 2];
  float2 vo = *(const float2*)&v_os[lane * 2];
  float2 va = *(const float2*)&v_a[lane * 2];
  float2 ar = *(const float2*)&adv_rs[lane * 2];
  float poo = wredsum(xo.x * vo.x + xo.y * vo.y);
  float pao = wredsum(xa.x * vo.x + xa.y * vo.y);
  float paa = wredsum(xa.x * va.x + xa.y * va.y);
  float poa = wredsum(xo.x * va.x + xo.y * va.y);
  float pov = wredsum(xo.x * ar.x + xo.y * ar.y);
  float pav = wredsum(xa.x * ar.x + xa.y * ar.y);
  if (lane == 0) {
    float db = disc_b[0], bv = small[640];
    out[4096 + 2 * i] = poo + db;
    out[4096 + 2 * i + 1] = pao + db;
    out[12288 + 2 * i] = paa + db;
    out[12288 + 2 * i + 1] = poa + db;
    out[544768 + i] = pov + bv;
    out[548864 + i] = pav + bv;
  }
}

// ---------------- decoder gather / final dot -----------------------------
__global__ __launch_bounds__(256) void gather_kernel(
    const float* __restrict__ x2o, const int* __restrict__ idx,
    unsigned short* __restrict__ z) {
  int i = blockIdx.x, c = threadIdx.x;
  int s = (c < 128) ? idx[i] : idx[4096 + i];
  z[(size_t)i * 256 + c] = f2bf(x2o[(size_t)s * 128 + (c & 127)]);
}

__global__ __launch_bounds__(256) void dec2_kernel(
    const unsigned short* __restrict__ hdec, const float* __restrict__ w2,
    const float* __restrict__ b2, float* __restrict__ out) {
  int lane = threadIdx.x & 63, wv = threadIdx.x >> 6;
  int i = blockIdx.x * 4 + wv;
  float s = 0.f;
#pragma unroll
  for (int q = 0; q < 8; ++q) {
    int f = lane + q * 64;
    s += bf2f(hdec[(size_t)i * 512 + f]) * w2[f];
  }
  s = wredsum(s);
  if (lane == 0) {
    float v = s + b2[0];
    out[552960 + i] = v;           // log1
    out[i] = 1.f / (1.f + __expf(-v));  // log
  }
}

// ---------------- host orchestration -------------------------------------
extern "C" void kernel_launch(void* const* d_in, const int* in_sizes, int n_in,
                              void* d_out, int out_size, void* d_ws, size_t ws_size,
                              hipStream_t stream) {
  const float* x_o = (const float*)d_in[0];
  const float* x_a = (const float*)d_in[1];
  const int* ei = (const int*)d_in[2];
  const int* idx = (const int*)d_in[3];
  const float* W1 = (const float*)d_in[4];
  const float* a1 = (const float*)d_in[5];
  const float* lin1 = (const float*)d_in[6];
  const float* res1 = (const float*)d_in[7];
  const float* W2 = (const float*)d_in[8];
  const float* a2 = (const float*)d_in[9];
  const float* lin2 = (const float*)d_in[10];
  const float* res2 = (const float*)d_in[11];
  const float* mlp1_w = (const float*)d_in[12];
  const float* mlp1_b = (const float*)d_in[13];
  const float* disc_w = (const float*)d_in[14];
  const float* disc_b = (const float*)d_in[15];
  const float* dec1_w = (const float*)d_in[16];
  const float* dec1_b = (const float*)d_in[17];
  const float* dec2_w = (const float*)d_in[18];
  const float* dec2_b = (const float*)d_in[19];
  const float* adv_w = (const float*)d_in[20];
  const float* adv_b = (const float*)d_in[21];
  float* out = (float*)d_out;

  char* w = (char*)d_ws;
  size_t off = 0;
  auto alloc = [&](size_t b) {
    char* p = w + off;
    off += (b + 255) & ~(size_t)255;
    return p;
  };
  unsigned long long* mb = (unsigned long long*)alloc((size_t)4096 * 64 * 8);
  unsigned short* x16 = (unsigned short*)alloc((size_t)8192 * 512 * 2);
  unsigned short* Wh1 = (unsigned short*)alloc((size_t)8192 * 1024 * 2);
  unsigned short* ho1 = (unsigned short*)alloc((size_t)8192 * 1024 * 2);
  unsigned short* h1 = (unsigned short*)alloc((size_t)8192 * 256 * 2);
  unsigned short* Wh2 = (unsigned short*)alloc((size_t)8192 * 512 * 2);
  unsigned short* ho2 = (unsigned short*)alloc((size_t)8192 * 512 * 2);
  float* x2a = (float*)alloc((size_t)4096 * 128 * 4);
  float* sd1 = (float*)alloc((size_t)8192 * 8 * 4);
  float* sd2 = (float*)alloc((size_t)8192 * 8 * 4);
  float* small = (float*)alloc(1024 * 4);
  int* rcnt = (int*)alloc(4096 * 4);
  int* rbase = (int*)alloc(4096 * 4);
  unsigned short* nbrg = (unsigned short*)alloc((size_t)(N_EDGES + 64) * 2);
  unsigned short* tW1 = (unsigned short*)alloc((size_t)524288 * 2);
  unsigned short* tlin1 = (unsigned short*)alloc((size_t)262144 * 2);
  unsigned short* tres1 = (unsigned short*)alloc((size_t)131072 * 2);
  unsigned short* tW2 = (unsigned short*)alloc((size_t)131072 * 2);
  unsigned short* tlin2 = (unsigned short*)alloc((size_t)65536 * 2);
  unsigned short* tres2 = (unsigned short*)alloc((size_t)32768 * 2);
  unsigned short* tdec1 = (unsigned short*)alloc((size_t)131072 * 2);
  unsigned short* z16 = (unsigned short*)alloc((size_t)4096 * 256 * 2);
  unsigned short* hdec = (unsigned short*)alloc((size_t)4096 * 512 * 2);

  hipMemsetAsync(mb, 0, (size_t)4096 * 64 * 8, stream);
  hipMemsetAsync(small, 0, 1024, stream);  // colsum accumulators
  scatter_kernel<<<1024, 256, 0, stream>>>(ei, mb, sd1, sd2);
  pack2_kernel<<<2272, 256, 0, stream>>>(W1, lin1, res1, W2, lin2, res2, dec1_w,
                                         x_o, x_a, tW1, tlin1, tres1, tW2,
                                         tlin2, tres2, tdec1, x16);
  csr_count<<<16, 256, 0, stream>>>(mb, rcnt);
  csr_scan<<<1, 64, 0, stream>>>(rcnt, rbase);
  csr_fill<<<1024, 256, 0, stream>>>(mb, rbase, nbrg);

  float* x2o_out = out + 20480;  // x2_o lives directly in d_out

  // ---- merged encode (rows 0..4095 = x_o, 4096..8191 = x_a) ----
  gemm128<<<dim3(8, 64), 256, 0, stream>>>(x16, tW1, 8192, 1024, 512, Wh1, a1, sd1, 256);
  attn2_kernel<256><<<8192, 256, 0, stream>>>(rcnt, rbase, nbrg, sd1, Wh1, ho1);
  gemm64dual<0><<<dim3(4, 128), 256, 0, stream>>>(ho1, tlin1, 1024, x16, tres1, 512, 256, h1, nullptr, nullptr);
  gemm128<<<dim3(4, 64), 256, 0, stream>>>(h1, tW2, 8192, 512, 256, Wh2, a2, sd2, 128);
  attn2_kernel<128><<<8192, 256, 0, stream>>>(rcnt, rbase, nbrg, sd2, Wh2, ho2);
  gemm64dual<1><<<dim3(2, 128), 256, 0, stream>>>(ho2, tlin2, 512, h1, tres2, 256, 128, nullptr, x2o_out, x2a);

  colsum_kernel<<<128, 128, 0, stream>>>(x2o_out, x2a, small);
  finalize_kernel<<<1, 128, 0, stream>>>(small, mlp1_w, mlp1_b, disc_w, adv_w, adv_b);
  pernode_kernel<<<1024, 256, 0, stream>>>(x2o_out, x2a, small, disc_b, out);
  gather_kernel<<<4096, 256, 0, stream>>>(x2o_out, idx, z16);
  gemm64<4><<<dim3(8, 64), 256, 0, stream>>>(z16, tdec1, 4096, 512, 256, hdec, dec1_b);
  dec2_kernel<<<1024, 256, 0, stream>>>(hdec, dec2_w, dec2_b, out);
}

// Round 10
// 212.855 us; speedup vs baseline: 1.1084x; 1.0178x over previous
//
#include <hip/hip_runtime.h>
#include <hip/hip_fp16.h>
#include <stdint.h>

#define N_NODES 4096
#define N_EDGES 131072

typedef __attribute__((ext_vector_type(8))) short short8;
typedef __attribute__((ext_vector_type(4))) float floatx4;

__device__ __forceinline__ float bf2f(unsigned short u) {
  union { unsigned u; float f; } v; v.u = ((unsigned)u) << 16; return v.f;
}
__device__ __forceinline__ unsigned short f2bf(float f) {
  union { float f; unsigned u; } v; v.f = f;
  unsigned r = 0x7FFFu + ((v.u >> 16) & 1u);
  return (unsigned short)((v.u + r) >> 16);
}
__device__ __forceinline__ float h2f_lo(unsigned w) {
  return __half2float(__ushort_as_half((unsigned short)(w & 0xffff)));
}
__device__ __forceinline__ float h2f_hi(unsigned w) {
  return __half2float(__ushort_as_half((unsigned short)(w >> 16)));
}
__device__ __forceinline__ float wredsum(float x) {
#pragma unroll
  for (int d = 32; d >= 1; d >>= 1) x += __shfl_xor(x, d);
  return x;
}
__device__ __forceinline__ float wredmax(float x) {
#pragma unroll
  for (int d = 32; d >= 1; d >>= 1) x = fmaxf(x, __shfl_xor(x, d));
  return x;
}
__device__ __forceinline__ void gload16(const void* g, void* l) {
  __builtin_amdgcn_global_load_lds(
      (const __attribute__((address_space(1))) unsigned*)g,
      (__attribute__((address_space(3))) unsigned*)l, 16, 0, 0);
}

// ============ 128x128-tile GEMM, BK=32, XOR-swizzled LDS (m97-style) ======
// Stores C as F16 (consumed only by attn via v_fma_mix). Fused epilogue:
// per-head src/dst projections (from f32 acc) via 16-lane shuffle reduce +
// atomicAdd into sdv (pre-zeroed).
__global__ __launch_bounds__(256) void gemm128(
    const unsigned short* __restrict__ A, const unsigned short* __restrict__ Bt,
    int M, int N, int K, unsigned short* __restrict__ Cb,
    const float* __restrict__ avec, float* __restrict__ sdv, int FO) {
  __shared__ __align__(16) unsigned short As[128 * 32];
  __shared__ __align__(16) unsigned short Bs[128 * 32];
  const int t = threadIdx.x, lane = t & 63, w = t >> 6;
  const int wr = w >> 1, wc = w & 1;
  const int n0 = blockIdx.x * 128, m0 = blockIdx.y * 128;
  floatx4 acc[4][4] = {};
  const int arow = t >> 2;                          // 0..63
  const int schunk = (t & 3) ^ ((arow >> 1) & 3);   // pre-swizzled src chunk

  for (int kt = 0; kt < K; kt += 32) {
    __syncthreads();
    gload16(A + (size_t)(m0 + arow) * K + kt + schunk * 8, &As[t * 8]);
    gload16(A + (size_t)(m0 + 64 + arow) * K + kt + schunk * 8, &As[(256 + t) * 8]);
    gload16(Bt + (size_t)(n0 + arow) * K + kt + schunk * 8, &Bs[t * 8]);
    gload16(Bt + (size_t)(n0 + 64 + arow) * K + kt + schunk * 8, &Bs[(256 + t) * 8]);
    __syncthreads();
    short8 af[4], bfr[4];
    const int koff = lane >> 4;
#pragma unroll
    for (int m = 0; m < 4; ++m) {
      const int r = wr * 64 + (lane & 15) + m * 16;
      af[m] = *(const short8*)&As[r * 32 + ((koff ^ ((r >> 1) & 3)) << 3)];
    }
#pragma unroll
    for (int n = 0; n < 4; ++n) {
      const int r = wc * 64 + (lane & 15) + n * 16;
      bfr[n] = *(const short8*)&Bs[r * 32 + ((koff ^ ((r >> 1) & 3)) << 3)];
    }
#pragma unroll
    for (int m = 0; m < 4; ++m)
#pragma unroll
      for (int n = 0; n < 4; ++n)
        acc[m][n] = __builtin_amdgcn_mfma_f32_16x16x32_bf16(af[m], bfr[n], acc[m][n], 0, 0, 0);
  }

  const int rb = m0 + wr * 64 + (lane >> 4) * 4;
  const int cb = n0 + wc * 64 + (lane & 15);
#pragma unroll
  for (int m = 0; m < 4; ++m)
#pragma unroll
    for (int n = 0; n < 4; ++n) {
      const int col = cb + n * 16;
#pragma unroll
      for (int r = 0; r < 4; ++r) {
        const int row = rb + m * 16 + r;
        Cb[(size_t)row * N + col] = __half_as_ushort(__float2half(acc[m][n][r]));
      }
    }

  if (avec) {  // fused src/dst projections
    const int h = n0 / FO;       // block lies within one head (128 | FO)
    const int cw0 = cb - h * FO; // col-in-head for n=0
    float as_[4], ad_[4];
#pragma unroll
    for (int n = 0; n < 4; ++n) {
      as_[n] = avec[h * 2 * FO + cw0 + n * 16];
      ad_[n] = avec[h * 2 * FO + FO + cw0 + n * 16];
    }
#pragma unroll
    for (int m = 0; m < 4; ++m)
#pragma unroll
      for (int r = 0; r < 4; ++r) {
        float sp = 0.f, dp = 0.f;
#pragma unroll
        for (int n = 0; n < 4; ++n) {
          sp += acc[m][n][r] * as_[n];
          dp += acc[m][n][r] * ad_[n];
        }
#pragma unroll
        for (int d = 1; d < 16; d <<= 1) {
          sp += __shfl_xor(sp, d);
          dp += __shfl_xor(dp, d);
        }
        if ((lane & 15) == 0) {
          const int row = rb + m * 16 + r;
          atomicAdd(&sdv[row * 8 + h], sp);
          atomicAdd(&sdv[row * 8 + 4 + h], dp);
        }
      }
  }
}

// ================= 64x64-tile GEMM, BK=64, XOR-swizzled LDS ===============
__device__ __forceinline__ void stage64(const unsigned short* __restrict__ G,
                                        unsigned short* lds, int row0, int K,
                                        int kt, int t) {
  const int l0 = t, l1 = t + 256;
  const int r0 = l0 >> 3, c0 = l0 & 7;
  const int r1 = l1 >> 3, c1 = l1 & 7;
  gload16(G + (size_t)(row0 + r0) * K + kt + ((c0 ^ (r0 & 7)) << 3), &lds[l0 * 8]);
  gload16(G + (size_t)(row0 + r1) * K + kt + ((c1 ^ (r1 & 7)) << 3), &lds[l1 * 8]);
}
__device__ __forceinline__ short8 frag64(const unsigned short* lds, int r, int c) {
  return *(const short8*)&lds[r * 64 + ((c ^ (r & 7)) << 3)];
}

// EP: 4 = relu(acc+bias[col]) -> bf16 (decoder layer 1)
template <int EP>
__global__ __launch_bounds__(256) void gemm64(
    const unsigned short* __restrict__ A, const unsigned short* __restrict__ Bt,
    int M, int N, int K, unsigned short* __restrict__ Cb,
    const float* __restrict__ bias) {
  __shared__ __align__(16) unsigned short As[64 * 64];
  __shared__ __align__(16) unsigned short Bs[64 * 64];
  const int t = threadIdx.x, lane = t & 63, w = t >> 6;
  const int wr = w >> 1, wc = w & 1;
  const int n0 = blockIdx.x * 64, m0 = blockIdx.y * 64;
  floatx4 acc[2][2] = {};

  for (int kt = 0; kt < K; kt += 64) {
    __syncthreads();
    stage64(A, As, m0, K, kt, t);
    stage64(Bt, Bs, n0, K, kt, t);
    __syncthreads();
    short8 af[2][2], bfv[2][2];
#pragma unroll
    for (int m = 0; m < 2; ++m) {
      const int ra = wr * 32 + (lane & 15) + m * 16;
#pragma unroll
      for (int kk = 0; kk < 2; ++kk)
        af[m][kk] = frag64(As, ra, (lane >> 4) + kk * 4);
    }
#pragma unroll
    for (int n = 0; n < 2; ++n) {
      const int rb = wc * 32 + (lane & 15) + n * 16;
#pragma unroll
      for (int kk = 0; kk < 2; ++kk)
        bfv[n][kk] = frag64(Bs, rb, (lane >> 4) + kk * 4);
    }
#pragma unroll
    for (int kk = 0; kk < 2; ++kk)
#pragma unroll
      for (int m = 0; m < 2; ++m)
#pragma unroll
        for (int n = 0; n < 2; ++n)
          acc[m][n] = __builtin_amdgcn_mfma_f32_16x16x32_bf16(af[m][kk], bfv[n][kk], acc[m][n], 0, 0, 0);
  }

  const int rb = m0 + wr * 32 + (lane >> 4) * 4;
  const int cb = n0 + wc * 32 + (lane & 15);
#pragma unroll
  for (int m = 0; m < 2; ++m)
#pragma unroll
    for (int n = 0; n < 2; ++n) {
      const int col = cb + n * 16;
#pragma unroll
      for (int r = 0; r < 4; ++r) {
        const int row = rb + m * 16 + r;
        float v = acc[m][n][r];
        if (EP == 4) { v += bias[col]; v = v > 0.f ? v : 0.f; }
        Cb[(size_t)row * N + col] = f2bf(v);
      }
    }
}

// C = relu(elu(A1@B1t) + A2@B2t).  EP0: bf16 store (merged).
// EP1: f32 store split — rows<4096 -> Cfo, rows>=4096 -> Cfa.
template <int EP>
__global__ __launch_bounds__(256) void gemm64dual(
    const unsigned short* __restrict__ A1, const unsigned short* __restrict__ B1t, int K1,
    const unsigned short* __restrict__ A2, const unsigned short* __restrict__ B2t, int K2,
    int N, unsigned short* __restrict__ Cb,
    float* __restrict__ Cfo, float* __restrict__ Cfa) {
  __shared__ __align__(16) unsigned short As[64 * 64];
  __shared__ __align__(16) unsigned short Bs[64 * 64];
  const int t = threadIdx.x, lane = t & 63, w = t >> 6;
  const int wr = w >> 1, wc = w & 1;
  const int n0 = blockIdx.x * 64, m0 = blockIdx.y * 64;
  floatx4 acc[2][2] = {};

#pragma unroll 1
  for (int pass = 0; pass < 2; ++pass) {
    const unsigned short* A = pass ? A2 : A1;
    const unsigned short* Bt = pass ? B2t : B1t;
    const int K = pass ? K2 : K1;
    for (int kt = 0; kt < K; kt += 64) {
      __syncthreads();
      stage64(A, As, m0, K, kt, t);
      stage64(Bt, Bs, n0, K, kt, t);
      __syncthreads();
      short8 af[2][2], bfv[2][2];
#pragma unroll
      for (int m = 0; m < 2; ++m) {
        const int ra = wr * 32 + (lane & 15) + m * 16;
#pragma unroll
        for (int kk = 0; kk < 2; ++kk)
          af[m][kk] = frag64(As, ra, (lane >> 4) + kk * 4);
      }
#pragma unroll
      for (int n = 0; n < 2; ++n) {
        const int rb = wc * 32 + (lane & 15) + n * 16;
#pragma unroll
        for (int kk = 0; kk < 2; ++kk)
          bfv[n][kk] = frag64(Bs, rb, (lane >> 4) + kk * 4);
      }
#pragma unroll
      for (int kk = 0; kk < 2; ++kk)
#pragma unroll
        for (int m = 0; m < 2; ++m)
#pragma unroll
          for (int n = 0; n < 2; ++n)
            acc[m][n] = __builtin_amdgcn_mfma_f32_16x16x32_bf16(af[m][kk], bfv[n][kk], acc[m][n], 0, 0, 0);
    }
    if (pass == 0) {  // elu via hw exp (bf16-precision-safe)
#pragma unroll
      for (int m = 0; m < 2; ++m)
#pragma unroll
        for (int n = 0; n < 2; ++n)
#pragma unroll
          for (int r = 0; r < 4; ++r) {
            float v = acc[m][n][r];
            acc[m][n][r] = v > 0.f ? v : __expf(v) - 1.f;
          }
    }
  }

  const int rb = m0 + wr * 32 + (lane >> 4) * 4;
  const int cb = n0 + wc * 32 + (lane & 15);
#pragma unroll
  for (int m = 0; m < 2; ++m)
#pragma unroll
    for (int n = 0; n < 2; ++n) {
      const int col = cb + n * 16;
#pragma unroll
      for (int r = 0; r < 4; ++r) {
        const int row = rb + m * 16 + r;
        float v = acc[m][n][r];
        v = v > 0.f ? v : 0.f;
        if (EP == 0) {
          Cb[(size_t)row * N + col] = f2bf(v);
        } else {
          float* bb = (row < 4096) ? Cfo : Cfa;
          bb[(size_t)(row & 4095) * N + col] = v;
        }
      }
    }
}

// ---------------- mask scatter + sd zero ---------------------------------
__global__ __launch_bounds__(256) void scatter_kernel(
    const int* __restrict__ ei, unsigned long long* __restrict__ mb,
    float* __restrict__ sd1, float* __restrict__ sd2) {
  int b = blockIdx.x;
  if (b < 512) {
    int e = b * 256 + threadIdx.x;
    int r = ei[e], c = ei[N_EDGES + e];
    atomicOr(&mb[(size_t)r * 64 + (c >> 6)], 1ull << (c & 63));
  } else {  // zero sd1 (65536 floats) then sd2
    int z = (b - 512) * 256 + threadIdx.x;
    if (z < 65536) sd1[z] = 0.f;
    else sd2[z - 65536] = 0.f;
  }
}

// ---------------- CSR build: count / scan / fill (deterministic) ----------
__global__ __launch_bounds__(256) void csr_count(
    const unsigned long long* __restrict__ mb, int* __restrict__ rcnt) {
  int r = blockIdx.x * 256 + threadIdx.x;  // 0..4095
  int c = 0;
#pragma unroll 8
  for (int w = 0; w < 64; ++w) c += __popcll(mb[(size_t)r * 64 + w]);
  rcnt[r] = c;
}

__global__ __launch_bounds__(64) void csr_scan(
    const int* __restrict__ rcnt, int* __restrict__ rbase) {
  int l = threadIdx.x;  // 0..63, each owns 64 rows
  int s = 0;
  for (int k = 0; k < 64; ++k) s += rcnt[l * 64 + k];
  int pre = s;
#pragma unroll
  for (int d = 1; d < 64; d <<= 1) {
    int v = __shfl_up(pre, d);
    if (l >= d) pre += v;
  }
  pre -= s;  // exclusive prefix of this lane's chunk
  int run = pre;
  for (int k = 0; k < 64; ++k) {
    rbase[l * 64 + k] = run;
    run += rcnt[l * 64 + k];
  }
}

__global__ __launch_bounds__(256) void csr_fill(
    const unsigned long long* __restrict__ mb, const int* __restrict__ rbase,
    unsigned short* __restrict__ nbrg) {
  int r = blockIdx.x * 4 + (threadIdx.x >> 6);
  int t = threadIdx.x & 63;
  unsigned long long wb = mb[(size_t)r * 64 + t];
  int pc = __popcll(wb);
  int inc = pc;
#pragma unroll
  for (int d = 1; d < 64; d <<= 1) {
    int v = __shfl_up(inc, d);
    if (t >= d) inc += v;
  }
  int off = rbase[r] + inc - pc;
  while (wb) {
    int b = __builtin_ctzll(wb);
    nbrg[off++] = (unsigned short)(t * 64 + b);
    wb &= wb - 1;
  }
}

// ---------------- weight pack: tiled f32->bf16 transposes + x casts -------
__global__ __launch_bounds__(256) void pack2_kernel(
    const float* W1, const float* lin1, const float* res1, const float* W2,
    const float* lin2, const float* res2, const float* dec1,
    const float* xo, const float* xa,
    unsigned short* dW1, unsigned short* dlin1, unsigned short* dres1,
    unsigned short* dW2, unsigned short* dlin2, unsigned short* dres2,
    unsigned short* ddec1, unsigned short* x16) {
  const int b = blockIdx.x, t = threadIdx.x;
  if (b >= 1248) {  // x_o / x_a f32 -> bf16 into merged [8192][512]
    int ib = b - 1248;
    const float* src = (ib < 512) ? xo : xa;
    unsigned short* dst = x16 + ((ib < 512) ? 0 : (size_t)4096 * 512);
    size_t base = (size_t)(ib & 511) * 4096;
#pragma unroll
    for (int q = 0; q < 4; ++q) {
      size_t o = base + q * 1024 + t * 4;
      float4 v = *(const float4*)&src[o];
      ushort4 u = {f2bf(v.x), f2bf(v.y), f2bf(v.z), f2bf(v.w)};
      *(ushort4*)&dst[o] = u;
    }
    return;
  }
  const float* src; unsigned short* dst; int K, F, nFt, tb;
  if (b < 512)       { int h = b >> 7;        src = W1 + h * 131072; dst = dW1 + h * 131072; K = 512;  F = 256; nFt = 8;  tb = b & 127; }
  else if (b < 768)  {                        src = lin1;            dst = dlin1;            K = 1024; F = 256; nFt = 8;  tb = b - 512; }
  else if (b < 896)  {                        src = res1;            dst = dres1;            K = 512;  F = 256; nFt = 8;  tb = b - 768; }
  else if (b < 1024) { int h = (b - 896) >> 5; src = W2 + h * 32768; dst = dW2 + h * 32768;  K = 256;  F = 128; nFt = 4;  tb = (b - 896) & 31; }
  else if (b < 1088) {                        src = lin2;            dst = dlin2;            K = 512;  F = 128; nFt = 4;  tb = b - 1024; }
  else if (b < 1120) {                        src = res2;            dst = dres2;            K = 256;  F = 128; nFt = 4;  tb = b - 1088; }
  else               {                        src = dec1;            dst = ddec1;            K = 256;  F = 512; nFt = 16; tb = b - 1120; }
  const int k0 = (tb / nFt) * 32, f0 = (tb % nFt) * 32;
  __shared__ float tile[32][33];
  {
    int r = t >> 3, c4 = (t & 7) * 4;
    float4 v = *(const float4*)&src[(size_t)(k0 + r) * F + f0 + c4];
    tile[r][c4] = v.x; tile[r][c4 + 1] = v.y; tile[r][c4 + 2] = v.z; tile[r][c4 + 3] = v.w;
  }
  __syncthreads();
  {
    int f = t >> 3, k4 = (t & 7) * 4;
    ushort4 u;
    u.x = f2bf(tile[k4 + 0][f]); u.y = f2bf(tile[k4 + 1][f]);
    u.z = f2bf(tile[k4 + 2][f]); u.w = f2bf(tile[k4 + 3][f]);
    *(ushort4*)&dst[(size_t)(f0 + f) * K + k0 + k4] = u;
  }
}

// ------- sparse attention, XCD-local (combo = head x encode = bid&7) ------
// Wh is F16; inner loop written to pattern-match v_fma_mix_f32 (f16 operand
// from hi/lo half, f32 accumulate). One wave per row; no barriers.
template <int FO>
__global__ __launch_bounds__(256) void attn2_kernel(
    const int* __restrict__ rcnt, const int* __restrict__ rbase,
    const unsigned short* __restrict__ nbrg, const float* __restrict__ sd,
    const unsigned short* __restrict__ Wh, unsigned short* __restrict__ outp) {
  constexpr int E = FO / 64;
  constexpr int W = 4 * FO;
  constexpr int CAP = 512;  // multiple of 8
  __shared__ __align__(16) unsigned short nb[4][CAP + 8];
  __shared__ __align__(16) float wg[4][CAP + 8];
  const int bid = blockIdx.x;
  const int combo = bid & 7, chunk = bid >> 3;
  const int h = combo & 3, e = combo >> 2;
  const int t = threadIdx.x, lane = t & 63, wv = t >> 6;
  const int r = chunk * 4 + wv;        // mask row 0..4095
  const int i = e * 4096 + r;          // Wh row
  const int jb = e * 4096;             // neighbor row offset
  const int cnt = rcnt[r], boff = rbase[r];
  const float src_i = sd[(size_t)i * 8 + h];
  float acc[E] = {};
  float inv = 1.f;

  if (cnt > 0) {
    const int limc = cnt < CAP ? cnt : CAP;
    if (cnt <= 64) {
      // single-pass softmax: each lane owns one neighbor
      int j = 0;
      float ee = -1e30f;
      if (lane < cnt) {
        j = nbrg[boff + lane];
        float x = src_i + sd[(size_t)(jb + j) * 8 + 4 + h];
        ee = x > 0.f ? x : 0.2f * x;
      }
      float m = wredmax(ee);
      float g = (lane < cnt) ? __expf(ee - m) : 0.f;
      nb[wv][lane] = (unsigned short)j;   // inactive lanes: j=0, weight 0
      wg[wv][lane] = g;
      inv = 1.f / wredsum(g);
    } else {
      // two-pass fallback (rare: cnt > 64)
      float m = -1e30f;
      for (int nn = lane; nn < cnt; nn += 64) {
        int j = nbrg[boff + nn];
        if (nn < CAP) nb[wv][nn] = (unsigned short)j;
        float x = src_i + sd[(size_t)(jb + j) * 8 + 4 + h];
        m = fmaxf(m, x > 0.f ? x : 0.2f * x);
      }
      m = wredmax(m);
      float ssum = 0.f;
      for (int nn = lane; nn < cnt; nn += 64) {
        int j = nbrg[boff + nn];
        float x = src_i + sd[(size_t)(jb + j) * 8 + 4 + h];
        float ee = x > 0.f ? x : 0.2f * x;
        float g = __expf(ee - m);
        if (nn < CAP) wg[wv][nn] = g;
        ssum += g;
      }
      ssum = wredsum(ssum);
      inv = 1.f / ssum;
      if (lane < 8) { nb[wv][limc + lane] = 0; wg[wv][limc + lane] = 0.f; }
      // tail beyond CAP: accumulate directly (weights recomputed)
      for (int nn = CAP; nn < cnt; ++nn) {
        int j = nbrg[boff + nn];
        float x = src_i + sd[(size_t)(jb + j) * 8 + 4 + h];
        float ee = x > 0.f ? x : 0.2f * x;
        float g = __expf(ee - m);
        const unsigned short* p = Wh + (size_t)(jb + j) * W + h * FO + lane * E;
#pragma unroll
        for (int q = 0; q < E; ++q)
          acc[q] = fmaf(__half2float(__ushort_as_half(p[q])), g, acc[q]);
      }
    }
    // pass 3: 8-wide unrolled gather; neighbor ids wave-uniform -> SGPR base
    const int ngroups = (limc + 7) >> 3;
    for (int g = 0; g < ngroups; ++g) {
      const int nn = g * 8;
      ushort4 ja = *(const ushort4*)&nb[wv][nn];
      ushort4 jb4 = *(const ushort4*)&nb[wv][nn + 4];
      float4 wa = *(const float4*)&wg[wv][nn];
      float4 wb4 = *(const float4*)&wg[wv][nn + 4];
      const int js[8] = {__builtin_amdgcn_readfirstlane((int)ja.x),
                         __builtin_amdgcn_readfirstlane((int)ja.y),
                         __builtin_amdgcn_readfirstlane((int)ja.z),
                         __builtin_amdgcn_readfirstlane((int)ja.w),
                         __builtin_amdgcn_readfirstlane((int)jb4.x),
                         __builtin_amdgcn_readfirstlane((int)jb4.y),
                         __builtin_amdgcn_readfirstlane((int)jb4.z),
                         __builtin_amdgcn_readfirstlane((int)jb4.w)};
      const float ws[8] = {wa.x, wa.y, wa.z, wa.w, wb4.x, wb4.y, wb4.z, wb4.w};
      if constexpr (E == 4) {
        uint2 rv[8];
#pragma unroll
        for (int q = 0; q < 8; ++q)
          rv[q] = *(const uint2*)(Wh + (size_t)(jb + js[q]) * W + h * FO + lane * 4);
#pragma unroll
        for (int q = 0; q < 8; ++q) {
          acc[0] = fmaf(h2f_lo(rv[q].x), ws[q], acc[0]);
          acc[1] = fmaf(h2f_hi(rv[q].x), ws[q], acc[1]);
          acc[2] = fmaf(h2f_lo(rv[q].y), ws[q], acc[2]);
          acc[3] = fmaf(h2f_hi(rv[q].y), ws[q], acc[3]);
        }
      } else {
        unsigned rv[8];
#pragma unroll
        for (int q = 0; q < 8; ++q)
          rv[q] = *(const unsigned*)(Wh + (size_t)(jb + js[q]) * W + h * FO + lane * 2);
#pragma unroll
        for (int q = 0; q < 8; ++q) {
          acc[0] = fmaf(h2f_lo(rv[q]), ws[q], acc[0]);
          acc[1] = fmaf(h2f_hi(rv[q]), ws[q], acc[1]);
        }
      }
    }
  } else {  // all-masked row: softmax over NEG row is uniform 1/N
    const float wgu = 1.f / 4096.f;
    for (int j = 0; j < N_NODES; ++j) {
      const unsigned short* p = Wh + (size_t)(jb + j) * W + h * FO + lane * E;
#pragma unroll
      for (int q = 0; q < E; ++q)
        acc[q] = fmaf(__half2float(__ushort_as_half(p[q])), wgu, acc[q]);
    }
  }
  unsigned short* op = outp + (size_t)i * W + h * FO + lane * E;
#pragma unroll
  for (int q = 0; q < E; ++q) {
    float v = acc[q] * inv;
    op[q] = f2bf(v > 0.f ? v : __expf(v) - 1.f);
  }
}

// ---------------- column sums of x2 (for mean) ---------------------------
__global__ __launch_bounds__(128) void colsum_kernel(
    const float* __restrict__ x2o, const float* __restrict__ x2a,
    float* __restrict__ small) {
  int b = blockIdx.x, f = threadIdx.x;
  const float* x = (b < 64) ? x2o : x2a;
  float* s = (b < 64) ? small : (small + 128);
  int r0 = (b & 63) * 64;
  float acc = 0.f;
  for (int r = 0; r < 64; ++r) acc += x[(size_t)(r0 + r) * 128 + f];
  atomicAdd(&s[f], acc);
}

// ---------------- tiny head math (single block) --------------------------
__global__ __launch_bounds__(128) void finalize_kernel(
    float* __restrict__ small, const float* __restrict__ mlp1_w,
    const float* __restrict__ mlp1_b, const float* __restrict__ disc_w,
    const float* __restrict__ adv_w, const float* __restrict__ adv_b) {
  __shared__ float so[128], sa[128], ho[128], ha[128];
  int f = threadIdx.x;
  so[f] = 1.f / (1.f + __expf(-small[f] * (1.f / 4096.f)));
  sa[f] = 1.f / (1.f + __expf(-small[128 + f] * (1.f / 4096.f)));
  __syncthreads();
  float aco = mlp1_b[f], aca = mlp1_b[f];
  for (int c = 0; c < 128; ++c) {
    aco += so[c] * mlp1_w[c * 128 + f];
    aca += sa[c] * mlp1_w[c * 128 + f];
  }
  ho[f] = aco;
  ha[f] = aca;
  __syncthreads();
  float vo = 0.f, va = 0.f, ar = 0.f;
  for (int c = 0; c < 128; ++c) {
    vo += disc_w[f * 128 + c] * ho[c];
    va += disc_w[f * 128 + c] * ha[c];
    ar += adv_w[f * 128 + c];
  }
  small[256 + f] = vo;
  small[384 + f] = va;
  small[512 + f] = ar;
  if (f == 0) {
    float b = 0.f;
    for (int c = 0; c < 128; ++c) b += adv_b[c];
    small[640] = b;
  }
}

// ---------------- per-node disc / adv outputs ----------------------------
__global__ __launch_bounds__(256) void pernode_kernel(
    const float* __restrict__ x2o, const float* __restrict__ x2a,
    const float* __restrict__ small, const float* __restrict__ disc_b,
    float* __restrict__ out) {
  const float* v_os = small + 256;
  const float* v_a = small + 384;
  const float* adv_rs = small + 512;
  int lane = threadIdx.x & 63, wv = threadIdx.x >> 6;
  int i = blockIdx.x * 4 + wv;
  float2 xo = *(const float2*)&x2o[(size_t)i * 128 + lane * 2];
  float2 xa = *(const float2*)&x2a[(size_t)i * 128 + lane * 2];
  float2 vo = *(const float2*)&v_os[lane * 2];
  float2 va = *(const float2*)&v_a[lane * 2];
  float2 ar = *(const float2*)&adv_rs[lane * 2];
  float poo = wredsum(xo.x * vo.x + xo.y * vo.y);
  float pao = wredsum(xa.x * vo.x + xa.y * vo.y);
  float paa = wredsum(xa.x * va.x + xa.y * va.y);
  float poa = wredsum(xo.x * va.x + xo.y * va.y);
  float pov = wredsum(xo.x * ar.x + xo.y * ar.y);
  float pav = wredsum(xa.x * ar.x + xa.y * ar.y);
  if (lane == 0) {
    float db = disc_b[0], bv = small[640];
    out[4096 + 2 * i] = poo + db;
    out[4096 + 2 * i + 1] = pao + db;
    out[12288 + 2 * i] = paa + db;
    out[12288 + 2 * i + 1] = poa + db;
    out[544768 + i] = pov + bv;
    out[548864 + i] = pav + bv;
  }
}

// ---------------- decoder gather / final dot -----------------------------
__global__ __launch_bounds__(256) void gather_kernel(
    const float* __restrict__ x2o, const int* __restrict__ idx,
    unsigned short* __restrict__ z) {
  int i = blockIdx.x, c = threadIdx.x;
  int s = (c < 128) ? idx[i] : idx[4096 + i];
  z[(size_t)i * 256 + c] = f2bf(x2o[(size_t)s * 128 + (c & 127)]);
}

__global__ __launch_bounds__(256) void dec2_kernel(
    const unsigned short* __restrict__ hdec, const float* __restrict__ w2,
    const float* __restrict__ b2, float* __restrict__ out) {
  int lane = threadIdx.x & 63, wv = threadIdx.x >> 6;
  int i = blockIdx.x * 4 + wv;
  float s = 0.f;
#pragma unroll
  for (int q = 0; q < 8; ++q) {
    int f = lane + q * 64;
    s += bf2f(hdec[(size_t)i * 512 + f]) * w2[f];
  }
  s = wredsum(s);
  if (lane == 0) {
    float v = s + b2[0];
    out[552960 + i] = v;           // log1
    out[i] = 1.f / (1.f + __expf(-v));  // log
  }
}

// ---------------- host orchestration -------------------------------------
extern "C" void kernel_launch(void* const* d_in, const int* in_sizes, int n_in,
                              void* d_out, int out_size, void* d_ws, size_t ws_size,
                              hipStream_t stream) {
  const float* x_o = (const float*)d_in[0];
  const float* x_a = (const float*)d_in[1];
  const int* ei = (const int*)d_in[2];
  const int* idx = (const int*)d_in[3];
  const float* W1 = (const float*)d_in[4];
  const float* a1 = (const float*)d_in[5];
  const float* lin1 = (const float*)d_in[6];
  const float* res1 = (const float*)d_in[7];
  const float* W2 = (const float*)d_in[8];
  const float* a2 = (const float*)d_in[9];
  const float* lin2 = (const float*)d_in[10];
  const float* res2 = (const float*)d_in[11];
  const float* mlp1_w = (const float*)d_in[12];
  const float* mlp1_b = (const float*)d_in[13];
  const float* disc_w = (const float*)d_in[14];
  const float* disc_b = (const float*)d_in[15];
  const float* dec1_w = (const float*)d_in[16];
  const float* dec1_b = (const float*)d_in[17];
  const float* dec2_w = (const float*)d_in[18];
  const float* dec2_b = (const float*)d_in[19];
  const float* adv_w = (const float*)d_in[20];
  const float* adv_b = (const float*)d_in[21];
  float* out = (float*)d_out;

  char* w = (char*)d_ws;
  size_t off = 0;
  auto alloc = [&](size_t b) {
    char* p = w + off;
    off += (b + 255) & ~(size_t)255;
    return p;
  };
  unsigned long long* mb = (unsigned long long*)alloc((size_t)4096 * 64 * 8);
  unsigned short* x16 = (unsigned short*)alloc((size_t)8192 * 512 * 2);
  unsigned short* Wh1 = (unsigned short*)alloc((size_t)8192 * 1024 * 2);
  unsigned short* ho1 = (unsigned short*)alloc((size_t)8192 * 1024 * 2);
  unsigned short* h1 = (unsigned short*)alloc((size_t)8192 * 256 * 2);
  unsigned short* Wh2 = (unsigned short*)alloc((size_t)8192 * 512 * 2);
  unsigned short* ho2 = (unsigned short*)alloc((size_t)8192 * 512 * 2);
  float* x2a = (float*)alloc((size_t)4096 * 128 * 4);
  float* sd1 = (float*)alloc((size_t)8192 * 8 * 4);
  float* sd2 = (float*)alloc((size_t)8192 * 8 * 4);
  float* small = (float*)alloc(1024 * 4);
  int* rcnt = (int*)alloc(4096 * 4);
  int* rbase = (int*)alloc(4096 * 4);
  unsigned short* nbrg = (unsigned short*)alloc((size_t)(N_EDGES + 64) * 2);
  unsigned short* tW1 = (unsigned short*)alloc((size_t)524288 * 2);
  unsigned short* tlin1 = (unsigned short*)alloc((size_t)262144 * 2);
  unsigned short* tres1 = (unsigned short*)alloc((size_t)131072 * 2);
  unsigned short* tW2 = (unsigned short*)alloc((size_t)131072 * 2);
  unsigned short* tlin2 = (unsigned short*)alloc((size_t)65536 * 2);
  unsigned short* tres2 = (unsigned short*)alloc((size_t)32768 * 2);
  unsigned short* tdec1 = (unsigned short*)alloc((size_t)131072 * 2);
  unsigned short* z16 = (unsigned short*)alloc((size_t)4096 * 256 * 2);
  unsigned short* hdec = (unsigned short*)alloc((size_t)4096 * 512 * 2);

  hipMemsetAsync(mb, 0, (size_t)4096 * 64 * 8, stream);
  hipMemsetAsync(small, 0, 1024, stream);  // colsum accumulators
  scatter_kernel<<<1024, 256, 0, stream>>>(ei, mb, sd1, sd2);
  pack2_kernel<<<2272, 256, 0, stream>>>(W1, lin1, res1, W2, lin2, res2, dec1_w,
                                         x_o, x_a, tW1, tlin1, tres1, tW2,
                                         tlin2, tres2, tdec1, x16);
  csr_count<<<16, 256, 0, stream>>>(mb, rcnt);
  csr_scan<<<1, 64, 0, stream>>>(rcnt, rbase);
  csr_fill<<<1024, 256, 0, stream>>>(mb, rbase, nbrg);

  float* x2o_out = out + 20480;  // x2_o lives directly in d_out

  // ---- merged encode (rows 0..4095 = x_o, 4096..8191 = x_a) ----
  gemm128<<<dim3(8, 64), 256, 0, stream>>>(x16, tW1, 8192, 1024, 512, Wh1, a1, sd1, 256);
  attn2_kernel<256><<<8192, 256, 0, stream>>>(rcnt, rbase, nbrg, sd1, Wh1, ho1);
  gemm64dual<0><<<dim3(4, 128), 256, 0, stream>>>(ho1, tlin1, 1024, x16, tres1, 512, 256, h1, nullptr, nullptr);
  gemm128<<<dim3(4, 64), 256, 0, stream>>>(h1, tW2, 8192, 512, 256, Wh2, a2, sd2, 128);
  attn2_kernel<128><<<8192, 256, 0, stream>>>(rcnt, rbase, nbrg, sd2, Wh2, ho2);
  gemm64dual<1><<<dim3(2, 128), 256, 0, stream>>>(ho2, tlin2, 512, h1, tres2, 256, 128, nullptr, x2o_out, x2a);

  colsum_kernel<<<128, 128, 0, stream>>>(x2o_out, x2a, small);
  finalize_kernel<<<1, 128, 0, stream>>>(small, mlp1_w, mlp1_b, disc_w, adv_w, adv_b);
  pernode_kernel<<<1024, 256, 0, stream>>>(x2o_out, x2a, small, disc_b, out);
  gather_kernel<<<4096, 256, 0, stream>>>(x2o_out, idx, z16);
  gemm64<4><<<dim3(8, 64), 256, 0, stream>>>(z16, tdec1, 4096, 512, 256, hdec, dec1_b);
  dec2_kernel<<<1024, 256, 0, stream>>>(hdec, dec2_w, dec2_b, out);
}